// Round 6
// baseline (375.608 us; speedup 1.0000x reference)
//
#include <hip/hip_runtime.h>
#include <hip/hip_bf16.h>

#define Nn 30000
#define Ee 400000
#define C1n 15000
#define E2n 100000
#define C2n 7500
#define Bb 16

// ---- workspace layout (float/u32 element offsets) ----
// zeroed region:
#define OFF_XPKEY   0         // C1*32 u32
#define OFF_POSSUM  480000    // C1*3
#define OFF_CNTC1   525000    // C1
#define OFF_BPMAX   540000    // C1 i32
#define OFF_X3KEY   555000    // C2*64 u32
#define OFF_B2MAX   1035000   // C2 i32
#define OFF_GSUM    1042500   // B*64
#define OFF_GCNT    1043524   // B
#define OFF_MAXABS  1043540   // 1 u32 (pad to 1043544)
#define OFF_DEG1    1043544   // N u32
#define OFF_FILL1   1073544   // N u32
#define OFF_DEG2    1103544   // C1 u32
#define OFF_FILL2   1118544   // C1 u32
#define ZERO_ELEMS  1133544
// non-zeroed:
#define OFF_RP1     1133544   // N+1 u32 (pad 30004)
#define OFF_RP2     1163548   // C1+1 u32 (pad 15004)
#define OFF_POSP    1178552   // C1*3
#define OFF_XP      1223552   // C1*32
#define OFF_W1T     1703552   // 32*192 bf16 = 3072 floats
#define OFF_W2T     1706624   // 64*896 bf16 = 28672 floats
#define OFF_EA1R    1735296   // E float4 (ea0,ea1,ea2,src_bits), dst-sorted
#define OFF_C2R     3335296   // E2 float4 (cart0,1,2,src_bits), dst-sorted
// total 3735296 floats ~ 15 MB

typedef __attribute__((ext_vector_type(8))) short short8;
typedef __attribute__((ext_vector_type(4))) float f32x4;

__device__ __forceinline__ unsigned fkey(float f) {
    unsigned u = __float_as_uint(f);
    return (u >> 31) ? ~u : (u | 0x80000000u);
}
__device__ __forceinline__ float funkey(unsigned k) {
    unsigned u = (k >> 31) ? (k ^ 0x80000000u) : ~k;
    return __uint_as_float(u);
}
__device__ __forceinline__ float elu(float a) { return a > 0.f ? a : expm1f(a); }

__device__ __forceinline__ unsigned short f2bf(float f) {
    unsigned u = __float_as_uint(f);
    unsigned lsb = (u >> 16) & 1u;
    u += 0x7fffu + lsb;  // round to nearest even
    return (unsigned short)(u >> 16);
}

// ==== CSR build: histogram (both graphs in one launch) ====
__global__ void hist_kernel(const int* __restrict__ ei, const int* __restrict__ ei2,
                            unsigned* __restrict__ deg1, unsigned* __restrict__ deg2) {
    int t = blockIdx.x * 256 + threadIdx.x;
    if (t < Ee) {
        atomicAdd(&deg1[ei[Ee + t]], 1u);
    } else if (t < Ee + E2n) {
        int e = t - Ee;
        atomicAdd(&deg2[ei2[E2n + e]], 1u);
    }
}

// single-block scans; block 0 -> graph1 (N), block 1 -> graph2 (C1)
__global__ __launch_bounds__(1024) void scan_both(
    const unsigned* __restrict__ deg1, unsigned* __restrict__ rp1,
    const unsigned* __restrict__ deg2, unsigned* __restrict__ rp2) {
    const unsigned* deg; unsigned* rp; int n;
    if (blockIdx.x == 0) { deg = deg1; rp = rp1; n = Nn; }
    else                 { deg = deg2; rp = rp2; n = C1n; }
    __shared__ unsigned ps[1024];
    const int t = threadIdx.x;
    const int chunk = (n + 1023) / 1024;
    const int lo = t * chunk;
    const int hi = (lo + chunk < n) ? lo + chunk : n;
    unsigned s = 0;
    for (int i = lo; i < hi; ++i) s += deg[i];
    ps[t] = s;
    __syncthreads();
    for (int off = 1; off < 1024; off <<= 1) {
        unsigned v = (t >= off) ? ps[t - off] : 0u;
        __syncthreads();
        ps[t] += v;
        __syncthreads();
    }
    unsigned run = (t > 0) ? ps[t - 1] : 0u;
    if (t == 0) rp[0] = 0u;
    for (int i = lo; i < hi; ++i) { run += deg[i]; rp[i + 1] = run; }
}

// ==== scatter1: edge attrs + src index into dst-sorted slots (16B payload) ====
__global__ void scatter1(const float* __restrict__ ea, const int* __restrict__ ei,
                         const unsigned* __restrict__ rp1, unsigned* __restrict__ fill1,
                         float4* __restrict__ EA1R) {
    int e = blockIdx.x * 256 + threadIdx.x;
    if (e >= Ee) return;
    int d = ei[Ee + e];
    unsigned p = rp1[d] + atomicAdd(&fill1[d], 1u);
    int src = ei[e];
    EA1R[p] = make_float4(ea[e * 3], ea[e * 3 + 1], ea[e * 3 + 2], __int_as_float(src));
}

// ==== precompute transposed bf16 weight panels (K-major per col) ====
__global__ void wt_kernel(const float* __restrict__ w1b, const float* __restrict__ b1b,
                          const float* __restrict__ root1, const float* __restrict__ bias1,
                          const float* __restrict__ w2b, const float* __restrict__ b2b,
                          const float* __restrict__ root2, const float* __restrict__ bias2,
                          unsigned short* __restrict__ W1T, unsigned short* __restrict__ W2T) {
    int t = blockIdx.x * 256 + threadIdx.x;
    if (t < 32 * 192) {
        int col = t / 192, p = t % 192;
        float v;
        if (p < 150)       { int k = p / 6, i = p % 6; v = w1b[k * 192 + i * 32 + col]; }
        else if (p < 156)  { int i = p - 150; v = b1b[i * 32 + col]; }
        else if (p < 162)  { v = root1[(p - 156) * 32 + col]; }
        else if (p == 162) { v = bias1[col]; }
        else v = 0.f;
        W1T[t] = f2bf(v);
    } else {
        int u = t - 32 * 192;
        if (u < 64 * 896) {
            int col = u / 896, p = u % 896;
            float v;
            if (p < 800)       { int k = p / 32, i = p % 32; v = w2b[k * 2048 + i * 64 + col]; }
            else if (p < 832)  { int i = p - 800; v = b2b[i * 64 + col]; }
            else if (p < 864)  { v = root2[(p - 832) * 64 + col]; }
            else if (p == 864) { v = bias2[col]; }
            else v = 0.f;
            W2T[u] = f2bf(v);
        }
    }
}

// ==== fused g1 + conv1 + pool1: per 16-dst tile, edge-gather rows into LDS
//      (bf16), MFMA [16x192]x[192x32], elu, pool1 atomics. ====
// LDS 6.4KB + launch_bounds(256,8): all 1875 blocks co-resident (32 waves/CU).
__global__ __launch_bounds__(256, 8) void g1conv1(
    const float* __restrict__ x, const float4* __restrict__ EA1R,
    const unsigned* __restrict__ rp1,
    const float* __restrict__ w1a, const float* __restrict__ b1a,
    const unsigned short* __restrict__ W1T,
    const float* __restrict__ pos, const int* __restrict__ batch, const int* __restrict__ cl1,
    unsigned* __restrict__ xpkey, float* __restrict__ possum,
    float* __restrict__ cntc1, int* __restrict__ bpmax) {
    __shared__ unsigned short As[16][200];  // bf16; row stride 400B (16B-aligned, 2-way banks: free)
    const int tid = threadIdx.x;
    const int w = tid >> 6;   // wave 0..3
    const int l = tid & 63;
    const int m = l & 15, q = l >> 4;
    int k_[3], i_[3];
#pragma unroll
    for (int r = 0; r < 3; ++r) { int j = r * 64 + l; k_[r] = j / 6; i_[r] = j % 6; }
    float wa0 = 0.f, wa1 = 0.f, wa2 = 0.f, ba0 = 0.f;
    if (l < 25) { wa0 = w1a[l]; wa1 = w1a[25 + l]; wa2 = w1a[50 + l]; ba0 = b1a[l]; }
    const int ntiles = Nn / 16;   // 1875
    for (int tile = blockIdx.x; tile < ntiles; tile += gridDim.x) {
        const int base = tile * 16;
        // ---- phase 1: each wave gathers 4 dst rows ----
#pragma unroll
        for (int s4 = 0; s4 < 4; ++s4) {
            const int row = w * 4 + s4;
            const int d = base + row;
            const unsigned e0 = rp1[d], e1 = rp1[d + 1];
            float acc[3] = {0.f, 0.f, 0.f};
            unsigned p = e0;
            for (; p + 4 <= e1; p += 4) {
                float4 ev[4];
#pragma unroll
                for (int b = 0; b < 4; ++b) ev[b] = EA1R[p + b];
                float xv[4][3];
#pragma unroll
                for (int b = 0; b < 4; ++b) {
                    const int sb = __float_as_int(ev[b].w) * 6;
                    xv[b][0] = x[sb + i_[0]];
                    xv[b][1] = x[sb + i_[1]];
                    xv[b][2] = x[sb + i_[2]];
                }
#pragma unroll
                for (int b = 0; b < 4; ++b) {
                    float a = ba0 + ev[b].x * wa0 + ev[b].y * wa1 + ev[b].z * wa2;
                    float hown = (l == 25) ? 1.f : fmaxf(a, 0.f);
                    acc[0] += __shfl(hown, k_[0], 64) * xv[b][0];
                    acc[1] += __shfl(hown, k_[1], 64) * xv[b][1];
                    acc[2] += __shfl(hown, k_[2], 64) * xv[b][2];
                }
            }
            for (; p < e1; ++p) {
                float4 ev = EA1R[p];
                const int sb = __float_as_int(ev.w) * 6;
                float a = ba0 + ev.x * wa0 + ev.y * wa1 + ev.z * wa2;
                float hown = (l == 25) ? 1.f : fmaxf(a, 0.f);
                acc[0] += __shfl(hown, k_[0], 64) * x[sb + i_[0]];
                acc[1] += __shfl(hown, k_[1], 64) * x[sb + i_[1]];
                acc[2] += __shfl(hown, k_[2], 64) * x[sb + i_[2]];
            }
            const float dinv = 1.f / fmaxf((float)(e1 - e0), 1.f);
#pragma unroll
            for (int r = 0; r < 3; ++r) {
                int j = r * 64 + l;
                float val;
                if (j < 156)       val = acc[r] * dinv;
                else if (j < 162)  val = x[d * 6 + (j - 156)];
                else if (j == 162) val = 1.f;
                else               val = 0.f;
                As[row][j] = f2bf(val);
            }
        }
        __syncthreads();
        // ---- phase 2: waves 0,1 MFMA the two 16-col quadrants; wave 2 pool aux ----
        if (w < 2) {
            f32x4 acc0 = {0.f, 0.f, 0.f, 0.f};
#pragma unroll
            for (int s = 0; s < 6; ++s) {
                short8 av = *reinterpret_cast<const short8*>(&As[m][s * 32 + q * 8]);
                short8 bv = *reinterpret_cast<const short8*>(&W1T[(w * 16 + m) * 192 + s * 32 + q * 8]);
                acc0 = __builtin_amdgcn_mfma_f32_16x16x32_bf16(av, bv, acc0, 0, 0, 0);
            }
#pragma unroll
            for (int r = 0; r < 4; ++r) {
                const int row = base + q * 4 + r;
                const int c = cl1[row];
                float v = elu(acc0[r]);
                atomicMax(&xpkey[c * 32 + w * 16 + m], fkey(v));
            }
        } else if (w == 2) {
            if (l < 16) {
                const int row = base + l;
                const int c = cl1[row];
#pragma unroll
                for (int j = 0; j < 3; ++j) atomicAdd(&possum[c * 3 + j], pos[row * 3 + j]);
                atomicAdd(&cntc1[c], 1.f);
                atomicMax(&bpmax[c], batch[row]);
            }
        }
        __syncthreads();
    }
}

__global__ void pool1_final(const unsigned* __restrict__ xpkey, const float* __restrict__ possum,
                            const float* __restrict__ cntc1, float* __restrict__ xp,
                            float* __restrict__ posp) {
    int t = blockIdx.x * 256 + threadIdx.x;
    if (t >= C1n * 32) return;
    int c = t >> 5, o = t & 31;
    unsigned k = xpkey[t];
    xp[t] = k ? funkey(k) : 0.f;
    if (o < 3) posp[c * 3 + o] = possum[c * 3 + o] / fmaxf(cntc1[c], 1.f);
}

// ==== scatter2 (+fused cart): cart from posp, src index, dst-sorted 16B payload ====
__global__ void scatter2(const float* __restrict__ posp, const int* __restrict__ ei2,
                         const unsigned* __restrict__ rp2, unsigned* __restrict__ fill2,
                         float4* __restrict__ C2R, unsigned* __restrict__ maxabs) {
    int e = blockIdx.x * 256 + threadIdx.x;
    float mx = 0.f;
    if (e < E2n) {
        int s = ei2[e], d = ei2[E2n + e];
        float c0 = posp[s * 3]     - posp[d * 3];
        float c1 = posp[s * 3 + 1] - posp[d * 3 + 1];
        float c2 = posp[s * 3 + 2] - posp[d * 3 + 2];
        mx = fmaxf(fmaxf(fabsf(c0), fabsf(c1)), fabsf(c2));
        unsigned p = rp2[d] + atomicAdd(&fill2[d], 1u);
        C2R[p] = make_float4(c0, c1, c2, __int_as_float(s));
    }
#pragma unroll
    for (int off = 32; off > 0; off >>= 1) mx = fmaxf(mx, __shfl_xor(mx, off));
    if ((threadIdx.x & 63) == 0) atomicMax(maxabs, __float_as_uint(mx));
}

// ==== fused g2 + conv2 + pool2: per 16-dst tile, edge-gather rows (K=896) into
//      LDS (bf16), MFMA [16x896]x[896x64], elu, pool2 atomics. ====
// LDS 28.9KB + launch_bounds(512,6): 3 blocks/CU (24 waves, 75%).
__global__ __launch_bounds__(512, 6) void g2conv2(
    const float* __restrict__ xp, const float4* __restrict__ C2R,
    const unsigned* __restrict__ maxabs, const unsigned* __restrict__ rp2,
    const float* __restrict__ w2a, const float* __restrict__ b2a,
    const unsigned short* __restrict__ W2T,
    const int* __restrict__ cl2, const int* __restrict__ bpmax,
    unsigned* __restrict__ x3key, int* __restrict__ b2max) {
    __shared__ unsigned short As[16][904];  // bf16; row stride 1808B (16B-aligned, 2-way banks)
    const int tid = threadIdx.x;
    const int w = tid >> 6;   // wave 0..7
    const int l = tid & 63;
    const int m = l & 15, q = l >> 4;
    const int i = l & 31, hp = l >> 5;
    float wa0 = 0.f, wa1 = 0.f, wa2 = 0.f, ba0 = 0.f;
    if (l < 25) { wa0 = w2a[l]; wa1 = w2a[25 + l]; wa2 = w2a[50 + l]; ba0 = b2a[l]; }
    const float inv = 0.5f / __uint_as_float(maxabs[0]);
    const int ntiles = (C1n + 15) / 16;   // 938
    for (int tile = blockIdx.x; tile < ntiles; tile += gridDim.x) {
        const int base = tile * 16;
        // ---- phase 1: each wave gathers 2 dst rows ----
#pragma unroll
        for (int s2 = 0; s2 < 2; ++s2) {
            const int row = w * 2 + s2;
            const int d = base + row;
            if (d < C1n) {
                const unsigned e0 = rp2[d], e1 = rp2[d + 1];
                float acc[13];
#pragma unroll
                for (int r = 0; r < 13; ++r) acc[r] = 0.f;
                unsigned p = e0;
                for (; p + 4 <= e1; p += 4) {
                    float4 cv[4];
#pragma unroll
                    for (int b = 0; b < 4; ++b) cv[b] = C2R[p + b];
                    float xv[4];
#pragma unroll
                    for (int b = 0; b < 4; ++b)
                        xv[b] = xp[__float_as_int(cv[b].w) * 32 + i];
#pragma unroll
                    for (int b = 0; b < 4; ++b) {
                        float a = ba0 + (cv[b].x * inv + 0.5f) * wa0 + (cv[b].y * inv + 0.5f) * wa1
                                      + (cv[b].z * inv + 0.5f) * wa2;
                        float hown = (l == 25) ? 1.f : fmaxf(a, 0.f);
#pragma unroll
                        for (int r = 0; r < 13; ++r)
                            acc[r] += __shfl(hown, 2 * r + hp, 64) * xv[b];
                    }
                }
                for (; p < e1; ++p) {
                    float4 cv = C2R[p];
                    float xv = xp[__float_as_int(cv.w) * 32 + i];
                    float a = ba0 + (cv.x * inv + 0.5f) * wa0 + (cv.y * inv + 0.5f) * wa1
                                  + (cv.z * inv + 0.5f) * wa2;
                    float hown = (l == 25) ? 1.f : fmaxf(a, 0.f);
#pragma unroll
                    for (int r = 0; r < 13; ++r)
                        acc[r] += __shfl(hown, 2 * r + hp, 64) * xv;
                }
                const float dinv = 1.f / fmaxf((float)(e1 - e0), 1.f);
#pragma unroll
                for (int r = 0; r < 13; ++r) As[row][r * 64 + l] = f2bf(acc[r] * dinv);
                As[row][832 + l] = f2bf((l < 32) ? xp[d * 32 + l] : (l == 32 ? 1.f : 0.f));
            } else {
#pragma unroll
                for (int r = 0; r < 13; ++r) As[row][r * 64 + l] = 0;
                As[row][832 + l] = 0;
            }
        }
        __syncthreads();
        // ---- phase 2: waves 0..3 MFMA the four 16-col quadrants; wave 4 aux ----
        if (w < 4) {
            f32x4 a4 = {0.f, 0.f, 0.f, 0.f};
#pragma unroll 4
            for (int s = 0; s < 28; ++s) {
                short8 av = *reinterpret_cast<const short8*>(&As[m][s * 32 + q * 8]);
                short8 bv = *reinterpret_cast<const short8*>(&W2T[(w * 16 + m) * 896 + s * 32 + q * 8]);
                a4 = __builtin_amdgcn_mfma_f32_16x16x32_bf16(av, bv, a4, 0, 0, 0);
            }
#pragma unroll
            for (int r = 0; r < 4; ++r) {
                const int row = base + q * 4 + r;
                if (row < C1n) {
                    const int c2 = cl2[row];
                    float v = elu(a4[r]);
                    atomicMax(&x3key[c2 * 64 + w * 16 + m], fkey(v));
                }
            }
        } else if (w == 4) {
            if (l < 16) {
                const int row = base + l;
                if (row < C1n) atomicMax(&b2max[cl2[row]], bpmax[row]);
            }
        }
        __syncthreads();
    }
}

// ---- two-stage batch reduction: LDS partials, then 1 global atomic/slot ----
__global__ __launch_bounds__(256) void gacc_kernel(
    const unsigned* __restrict__ x3key, const int* __restrict__ b2max,
    float* __restrict__ gsum, float* __restrict__ gcnt) {
    __shared__ float ls[Bb * 64];
    __shared__ float lc[Bb];
    const int t = threadIdx.x;
    for (int i = t; i < Bb * 64; i += 256) ls[i] = 0.f;
    if (t < Bb) lc[t] = 0.f;
    __syncthreads();
    const int o = t & 63;
    const int cs = t >> 6;
    for (int c = blockIdx.x * 4 + cs; c < C2n; c += gridDim.x * 4) {
        int b = b2max[c];
        unsigned k = x3key[c * 64 + o];
        float v = k ? funkey(k) : 0.f;
        atomicAdd(&ls[b * 64 + o], v);
        if (o == 0) atomicAdd(&lc[b], 1.f);
    }
    __syncthreads();
    for (int i = t; i < Bb * 64; i += 256) {
        float v = ls[i];
        if (v != 0.f) atomicAdd(&gsum[i], v);
    }
    if (t < Bb) {
        float v = lc[t];
        if (v != 0.f) atomicAdd(&gcnt[t], v);
    }
}

__global__ void head_kernel(const float* __restrict__ gsum, const float* __restrict__ gcnt,
                            const float* __restrict__ fc1w, const float* __restrict__ fc1b,
                            const float* __restrict__ fc2w, const float* __restrict__ fc2b,
                            float* __restrict__ out) {
    __shared__ float g[16 * 64];
    __shared__ float hb[16 * 128];
    __shared__ float lg[16 * 10];
    __shared__ float rowm[16];
    int t = threadIdx.x;
    for (int idx = t; idx < 16 * 64; idx += 256) {
        int b = idx >> 6;
        g[idx] = gsum[idx] / fmaxf(gcnt[b], 1.f);
    }
    __syncthreads();
    for (int idx = t; idx < 16 * 128; idx += 256) {
        int b = idx >> 7, j = idx & 127;
        float a = fc1b[j];
        for (int i = 0; i < 64; ++i) a += g[b * 64 + i] * fc1w[i * 128 + j];
        hb[idx] = elu(a);
    }
    __syncthreads();
    for (int idx = t; idx < 160; idx += 256) {
        int b = idx / 10, c = idx % 10;
        float a = fc2b[c];
        for (int i = 0; i < 128; ++i) a += hb[b * 128 + i] * fc2w[i * 10 + c];
        lg[idx] = a;
    }
    __syncthreads();
    if (t < 16) {
        float m = -1e30f;
        for (int c = 0; c < 10; ++c) m = fmaxf(m, lg[t * 10 + c]);
        float s = 0.f;
        for (int c = 0; c < 10; ++c) s += expf(lg[t * 10 + c] - m);
        rowm[t] = m + logf(s);
    }
    __syncthreads();
    for (int idx = t; idx < 160; idx += 256) out[idx] = lg[idx] - rowm[idx / 10];
}

extern "C" void kernel_launch(void* const* d_in, const int* in_sizes, int n_in,
                              void* d_out, int out_size, void* d_ws, size_t ws_size,
                              hipStream_t stream) {
    const float* x     = (const float*)d_in[0];
    const float* ea    = (const float*)d_in[1];
    const float* pos   = (const float*)d_in[2];
    const int*   ei    = (const int*)d_in[3];
    const int*   batch = (const int*)d_in[4];
    const int*   cl1   = (const int*)d_in[5];
    const int*   ei2   = (const int*)d_in[6];
    const int*   cl2   = (const int*)d_in[7];
    const float* w1a   = (const float*)d_in[8];
    const float* b1a   = (const float*)d_in[9];
    const float* w1b   = (const float*)d_in[10];
    const float* b1b   = (const float*)d_in[11];
    const float* root1 = (const float*)d_in[12];
    const float* bias1 = (const float*)d_in[13];
    const float* w2a   = (const float*)d_in[14];
    const float* b2a   = (const float*)d_in[15];
    const float* w2b   = (const float*)d_in[16];
    const float* b2b   = (const float*)d_in[17];
    const float* root2 = (const float*)d_in[18];
    const float* bias2 = (const float*)d_in[19];
    const float* fc1w  = (const float*)d_in[20];
    const float* fc1b  = (const float*)d_in[21];
    const float* fc2w  = (const float*)d_in[22];
    const float* fc2b  = (const float*)d_in[23];
    float* out = (float*)d_out;

    float* ws = (float*)d_ws;
    unsigned* xpkey  = (unsigned*)(ws + OFF_XPKEY);
    float*    possum = ws + OFF_POSSUM;
    float*    cntc1  = ws + OFF_CNTC1;
    int*      bpmax  = (int*)(ws + OFF_BPMAX);
    unsigned* x3key  = (unsigned*)(ws + OFF_X3KEY);
    int*      b2max  = (int*)(ws + OFF_B2MAX);
    float*    gsum   = ws + OFF_GSUM;
    float*    gcnt   = ws + OFF_GCNT;
    unsigned* maxabs = (unsigned*)(ws + OFF_MAXABS);
    unsigned* deg1   = (unsigned*)(ws + OFF_DEG1);
    unsigned* fill1  = (unsigned*)(ws + OFF_FILL1);
    unsigned* deg2   = (unsigned*)(ws + OFF_DEG2);
    unsigned* fill2  = (unsigned*)(ws + OFF_FILL2);
    unsigned* rp1    = (unsigned*)(ws + OFF_RP1);
    unsigned* rp2    = (unsigned*)(ws + OFF_RP2);
    float*    posp   = ws + OFF_POSP;
    float*    xp     = ws + OFF_XP;
    unsigned short* W1T = (unsigned short*)(ws + OFF_W1T);
    unsigned short* W2T = (unsigned short*)(ws + OFF_W2T);
    float4*   EA1R  = (float4*)(ws + OFF_EA1R);
    float4*   C2R   = (float4*)(ws + OFF_C2R);

    hipMemsetAsync(ws, 0, (size_t)ZERO_ELEMS * 4, stream);

    wt_kernel<<<248, 256, 0, stream>>>(w1b, b1b, root1, bias1, w2b, b2b, root2, bias2, W1T, W2T);
    hist_kernel<<<(Ee + E2n + 255) / 256, 256, 0, stream>>>(ei, ei2, deg1, deg2);
    scan_both<<<2, 1024, 0, stream>>>(deg1, rp1, deg2, rp2);
    scatter1<<<(Ee + 255) / 256, 256, 0, stream>>>(ea, ei, rp1, fill1, EA1R);
    g1conv1<<<1875, 256, 0, stream>>>(x, EA1R, rp1, w1a, b1a, W1T, pos, batch, cl1,
                                      xpkey, possum, cntc1, bpmax);
    pool1_final<<<(C1n * 32 + 255) / 256, 256, 0, stream>>>(xpkey, possum, cntc1, xp, posp);
    scatter2<<<(E2n + 255) / 256, 256, 0, stream>>>(posp, ei2, rp2, fill2, C2R, maxabs);
    g2conv2<<<938, 512, 0, stream>>>(xp, C2R, maxabs, rp2, w2a, b2a, W2T, cl2, bpmax,
                                     x3key, b2max);
    gacc_kernel<<<32, 256, 0, stream>>>(x3key, b2max, gsum, gcnt);
    head_kernel<<<1, 256, 0, stream>>>(gsum, gcnt, fc1w, fc1b, fc2w, fc2b, out);
}

// Round 7
// 349.027 us; speedup vs baseline: 1.0762x; 1.0762x over previous
//
#include <hip/hip_runtime.h>
#include <hip/hip_bf16.h>

#define Nn 30000
#define Ee 400000
#define C1n 15000
#define E2n 100000
#define C2n 7500
#define Bb 16

// ---- workspace layout (float/u32 element offsets) ----
// zeroed region:
#define OFF_XPKEY   0         // C1*32 u32
#define OFF_POSSUM  480000    // C1*3
#define OFF_CNTC1   525000    // C1
#define OFF_BPMAX   540000    // C1 i32
#define OFF_X3KEY   555000    // C2*64 u32
#define OFF_B2MAX   1035000   // C2 i32
#define OFF_GSUM    1042500   // B*64
#define OFF_GCNT    1043524   // B
#define OFF_MAXABS  1043540   // 1 u32 (pad to 1043544)
#define OFF_DEG1    1043544   // N u32
#define OFF_FILL1   1073544   // N u32
#define OFF_DEG2    1103544   // C1 u32
#define OFF_FILL2   1118544   // C1 u32
#define ZERO_ELEMS  1133544
// non-zeroed:
#define OFF_RP1     1133544   // N+1 u32 (pad 30004)
#define OFF_RP2     1163548   // C1+1 u32 (pad 15004)
#define OFF_POSP    1178552   // C1*3
#define OFF_XP      1223552   // C1*32
#define OFF_W1T     1703552   // 32*224 bf16 = 3584 floats (padded K: j=k*8+i)
#define OFF_W2T     1707136   // 64*896 bf16 = 28672 floats
#define OFF_EA1R    1735808   // E float4 (ea0,ea1,ea2,src_bits), dst-sorted
#define OFF_C2R     3335808   // E2 float4 (cart0,1,2,src_bits), dst-sorted
// total 3735808 floats ~ 15 MB

typedef __attribute__((ext_vector_type(8))) short short8;
typedef __attribute__((ext_vector_type(4))) float f32x4;

__device__ __forceinline__ unsigned fkey(float f) {
    unsigned u = __float_as_uint(f);
    return (u >> 31) ? ~u : (u | 0x80000000u);
}
__device__ __forceinline__ float funkey(unsigned k) {
    unsigned u = (k >> 31) ? (k ^ 0x80000000u) : ~k;
    return __uint_as_float(u);
}
__device__ __forceinline__ float elu(float a) { return a > 0.f ? a : expm1f(a); }

__device__ __forceinline__ unsigned short f2bf(float f) {
    unsigned u = __float_as_uint(f);
    unsigned lsb = (u >> 16) & 1u;
    u += 0x7fffu + lsb;  // round to nearest even
    return (unsigned short)(u >> 16);
}

// ==== CSR build: histogram (both graphs in one launch) ====
__global__ void hist_kernel(const int* __restrict__ ei, const int* __restrict__ ei2,
                            unsigned* __restrict__ deg1, unsigned* __restrict__ deg2) {
    int t = blockIdx.x * 256 + threadIdx.x;
    if (t < Ee) {
        atomicAdd(&deg1[ei[Ee + t]], 1u);
    } else if (t < Ee + E2n) {
        int e = t - Ee;
        atomicAdd(&deg2[ei2[E2n + e]], 1u);
    }
}

// single-block scans; block 0 -> graph1 (N), block 1 -> graph2 (C1)
__global__ __launch_bounds__(1024) void scan_both(
    const unsigned* __restrict__ deg1, unsigned* __restrict__ rp1,
    const unsigned* __restrict__ deg2, unsigned* __restrict__ rp2) {
    const unsigned* deg; unsigned* rp; int n;
    if (blockIdx.x == 0) { deg = deg1; rp = rp1; n = Nn; }
    else                 { deg = deg2; rp = rp2; n = C1n; }
    __shared__ unsigned ps[1024];
    const int t = threadIdx.x;
    const int chunk = (n + 1023) / 1024;
    const int lo = t * chunk;
    const int hi = (lo + chunk < n) ? lo + chunk : n;
    unsigned s = 0;
    for (int i = lo; i < hi; ++i) s += deg[i];
    ps[t] = s;
    __syncthreads();
    for (int off = 1; off < 1024; off <<= 1) {
        unsigned v = (t >= off) ? ps[t - off] : 0u;
        __syncthreads();
        ps[t] += v;
        __syncthreads();
    }
    unsigned run = (t > 0) ? ps[t - 1] : 0u;
    if (t == 0) rp[0] = 0u;
    for (int i = lo; i < hi; ++i) { run += deg[i]; rp[i + 1] = run; }
}

// ==== scatter1: edge attrs + src index into dst-sorted slots (16B payload) ====
__global__ void scatter1(const float* __restrict__ ea, const int* __restrict__ ei,
                         const unsigned* __restrict__ rp1, unsigned* __restrict__ fill1,
                         float4* __restrict__ EA1R) {
    int e = blockIdx.x * 256 + threadIdx.x;
    if (e >= Ee) return;
    int d = ei[Ee + e];
    unsigned p = rp1[d] + atomicAdd(&fill1[d], 1u);
    int src = ei[e];
    EA1R[p] = make_float4(ea[e * 3], ea[e * 3 + 1], ea[e * 3 + 2], __int_as_float(src));
}

// ==== precompute transposed bf16 weight panels (K-major per col) ====
// W1T: K=224, j=k*8+i padded layout. p<208: (k=p>>3,i=p&7) -> w1b/b1b (0 for i>=6);
//      208..213: root1; 214: bias1; 215..223: 0.
// W2T: unchanged (K=896, j=k*32+i).
__global__ void wt_kernel(const float* __restrict__ w1b, const float* __restrict__ b1b,
                          const float* __restrict__ root1, const float* __restrict__ bias1,
                          const float* __restrict__ w2b, const float* __restrict__ b2b,
                          const float* __restrict__ root2, const float* __restrict__ bias2,
                          unsigned short* __restrict__ W1T, unsigned short* __restrict__ W2T) {
    int t = blockIdx.x * 256 + threadIdx.x;
    if (t < 32 * 224) {
        int col = t / 224, p = t % 224;
        float v = 0.f;
        if (p < 208) {
            int k = p >> 3, i = p & 7;
            if (i < 6) v = (k < 25) ? w1b[k * 192 + i * 32 + col] : b1b[i * 32 + col];
        }
        else if (p < 214)  { v = root1[(p - 208) * 32 + col]; }
        else if (p == 214) { v = bias1[col]; }
        W1T[t] = f2bf(v);
    } else {
        int u = t - 32 * 224;
        if (u < 64 * 896) {
            int col = u / 896, p = u % 896;
            float v;
            if (p < 800)       { int k = p / 32, i = p % 32; v = w2b[k * 2048 + i * 64 + col]; }
            else if (p < 832)  { int i = p - 800; v = b2b[i * 64 + col]; }
            else if (p < 864)  { v = root2[(p - 832) * 64 + col]; }
            else if (p == 864) { v = bias2[col]; }
            else v = 0.f;
            W2T[u] = f2bf(v);
        }
    }
}

// ==== fused g1 + conv1 + pool1, padded-K layout: j=k*8+i so each lane needs
//      exactly ONE x element (i=l&7) per edge -> 1 gather/edge instead of 3. ====
__global__ __launch_bounds__(256, 8) void g1conv1(
    const float* __restrict__ x, const float4* __restrict__ EA1R,
    const unsigned* __restrict__ rp1,
    const float* __restrict__ w1a, const float* __restrict__ b1a,
    const unsigned short* __restrict__ W1T,
    const float* __restrict__ pos, const int* __restrict__ batch, const int* __restrict__ cl1,
    unsigned* __restrict__ xpkey, float* __restrict__ possum,
    float* __restrict__ cntc1, int* __restrict__ bpmax) {
    __shared__ unsigned short As[16][232];  // bf16; stride 464B -> 2-way banks on b128 reads
    const int tid = threadIdx.x;
    const int w = tid >> 6;   // wave 0..3
    const int l = tid & 63;
    const int m = l & 15, q = l >> 4;
    const int i8 = l & 7;          // lane's x column (all r), i8>=6 -> zero pad
    const int kq = l >> 3;         // k offset within each r-block
    float wa0 = 0.f, wa1 = 0.f, wa2 = 0.f, ba0 = 0.f;
    if (l < 25) { wa0 = w1a[l]; wa1 = w1a[25 + l]; wa2 = w1a[50 + l]; ba0 = b1a[l]; }
    const int ntiles = Nn / 16;   // 1875
    for (int tile = blockIdx.x; tile < ntiles; tile += gridDim.x) {
        const int base = tile * 16;
        // ---- phase 1: each wave gathers 4 dst rows ----
#pragma unroll
        for (int s4 = 0; s4 < 4; ++s4) {
            const int row = w * 4 + s4;
            const int d = base + row;
            const unsigned e0 = rp1[d], e1 = rp1[d + 1];
            float acc0 = 0.f, acc1 = 0.f, acc2 = 0.f, acc3 = 0.f;
            unsigned p = e0;
            for (; p + 4 <= e1; p += 4) {
                float4 ev[4];
#pragma unroll
                for (int b = 0; b < 4; ++b) ev[b] = EA1R[p + b];
                float xm[4];
#pragma unroll
                for (int b = 0; b < 4; ++b) {
                    const int sb = __float_as_int(ev[b].w) * 6;
                    xm[b] = (i8 < 6) ? x[sb + i8] : 0.f;   // ONE gather per edge
                }
#pragma unroll
                for (int b = 0; b < 4; ++b) {
                    float a = ba0 + ev[b].x * wa0 + ev[b].y * wa1 + ev[b].z * wa2;
                    float hown = (l == 25) ? 1.f : fmaxf(a, 0.f);
                    acc0 += __shfl(hown, kq, 64) * xm[b];
                    acc1 += __shfl(hown, 8 + kq, 64) * xm[b];
                    acc2 += __shfl(hown, 16 + kq, 64) * xm[b];
                    acc3 += __shfl(hown, 24 + kq, 64) * xm[b];  // valid for lanes l<16 (k=24,25)
                }
            }
            for (; p < e1; ++p) {
                float4 ev = EA1R[p];
                const int sb = __float_as_int(ev.w) * 6;
                float xm = (i8 < 6) ? x[sb + i8] : 0.f;
                float a = ba0 + ev.x * wa0 + ev.y * wa1 + ev.z * wa2;
                float hown = (l == 25) ? 1.f : fmaxf(a, 0.f);
                acc0 += __shfl(hown, kq, 64) * xm;
                acc1 += __shfl(hown, 8 + kq, 64) * xm;
                acc2 += __shfl(hown, 16 + kq, 64) * xm;
                acc3 += __shfl(hown, 24 + kq, 64) * xm;
            }
            const float dinv = 1.f / fmaxf((float)(e1 - e0), 1.f);
            As[row][l] = f2bf(acc0 * dinv);          // j 0..63   (k 0..7)
            As[row][64 + l] = f2bf(acc1 * dinv);     // j 64..127 (k 8..15)
            As[row][128 + l] = f2bf(acc2 * dinv);    // j 128..191(k 16..23)
            if (l < 16) {
                As[row][192 + l] = f2bf(acc3 * dinv);  // j 192..207 (k 24..25)
                float tail;
                if (l < 6)       tail = x[d * 6 + l];   // root slot
                else if (l == 6) tail = 1.f;            // bias slot (j=214)
                else             tail = 0.f;
                As[row][208 + l] = f2bf(tail);
            }
        }
        __syncthreads();
        // ---- phase 2: waves 0,1 MFMA the two 16-col quadrants; wave 2 pool aux ----
        if (w < 2) {
            f32x4 acc = {0.f, 0.f, 0.f, 0.f};
#pragma unroll
            for (int s = 0; s < 7; ++s) {
                short8 av = *reinterpret_cast<const short8*>(&As[m][s * 32 + q * 8]);
                short8 bv = *reinterpret_cast<const short8*>(&W1T[(w * 16 + m) * 224 + s * 32 + q * 8]);
                acc = __builtin_amdgcn_mfma_f32_16x16x32_bf16(av, bv, acc, 0, 0, 0);
            }
#pragma unroll
            for (int r = 0; r < 4; ++r) {
                const int row = base + q * 4 + r;
                const int c = cl1[row];
                float v = elu(acc[r]);
                atomicMax(&xpkey[c * 32 + w * 16 + m], fkey(v));
            }
        } else if (w == 2) {
            if (l < 16) {
                const int row = base + l;
                const int c = cl1[row];
#pragma unroll
                for (int j = 0; j < 3; ++j) atomicAdd(&possum[c * 3 + j], pos[row * 3 + j]);
                atomicAdd(&cntc1[c], 1.f);
                atomicMax(&bpmax[c], batch[row]);
            }
        }
        __syncthreads();
    }
}

__global__ void pool1_final(const unsigned* __restrict__ xpkey, const float* __restrict__ possum,
                            const float* __restrict__ cntc1, float* __restrict__ xp,
                            float* __restrict__ posp) {
    int t = blockIdx.x * 256 + threadIdx.x;
    if (t >= C1n * 32) return;
    int c = t >> 5, o = t & 31;
    unsigned k = xpkey[t];
    xp[t] = k ? funkey(k) : 0.f;
    if (o < 3) posp[c * 3 + o] = possum[c * 3 + o] / fmaxf(cntc1[c], 1.f);
}

// ==== scatter2 (+fused cart): cart from posp, src index, dst-sorted 16B payload ====
__global__ void scatter2(const float* __restrict__ posp, const int* __restrict__ ei2,
                         const unsigned* __restrict__ rp2, unsigned* __restrict__ fill2,
                         float4* __restrict__ C2R, unsigned* __restrict__ maxabs) {
    int e = blockIdx.x * 256 + threadIdx.x;
    float mx = 0.f;
    if (e < E2n) {
        int s = ei2[e], d = ei2[E2n + e];
        float c0 = posp[s * 3]     - posp[d * 3];
        float c1 = posp[s * 3 + 1] - posp[d * 3 + 1];
        float c2 = posp[s * 3 + 2] - posp[d * 3 + 2];
        mx = fmaxf(fmaxf(fabsf(c0), fabsf(c1)), fabsf(c2));
        unsigned p = rp2[d] + atomicAdd(&fill2[d], 1u);
        C2R[p] = make_float4(c0, c1, c2, __int_as_float(s));
    }
#pragma unroll
    for (int off = 32; off > 0; off >>= 1) mx = fmaxf(mx, __shfl_xor(mx, off));
    if ((threadIdx.x & 63) == 0) atomicMax(maxabs, __float_as_uint(mx));
}

// ==== fused g2 + conv2 + pool2: per 16-dst tile, edge-gather rows (K=896) into
//      LDS (bf16), MFMA [16x896]x[896x64], elu, pool2 atomics. ====
__global__ __launch_bounds__(512, 6) void g2conv2(
    const float* __restrict__ xp, const float4* __restrict__ C2R,
    const unsigned* __restrict__ maxabs, const unsigned* __restrict__ rp2,
    const float* __restrict__ w2a, const float* __restrict__ b2a,
    const unsigned short* __restrict__ W2T,
    const int* __restrict__ cl2, const int* __restrict__ bpmax,
    unsigned* __restrict__ x3key, int* __restrict__ b2max) {
    __shared__ unsigned short As[16][904];  // bf16; row stride 1808B (16B-aligned, 2-way banks)
    const int tid = threadIdx.x;
    const int w = tid >> 6;   // wave 0..7
    const int l = tid & 63;
    const int m = l & 15, q = l >> 4;
    const int i = l & 31, hp = l >> 5;
    float wa0 = 0.f, wa1 = 0.f, wa2 = 0.f, ba0 = 0.f;
    if (l < 25) { wa0 = w2a[l]; wa1 = w2a[25 + l]; wa2 = w2a[50 + l]; ba0 = b2a[l]; }
    const float inv = 0.5f / __uint_as_float(maxabs[0]);
    const int ntiles = (C1n + 15) / 16;   // 938
    for (int tile = blockIdx.x; tile < ntiles; tile += gridDim.x) {
        const int base = tile * 16;
        // ---- phase 1: each wave gathers 2 dst rows ----
#pragma unroll
        for (int s2 = 0; s2 < 2; ++s2) {
            const int row = w * 2 + s2;
            const int d = base + row;
            if (d < C1n) {
                const unsigned e0 = rp2[d], e1 = rp2[d + 1];
                float acc[13];
#pragma unroll
                for (int r = 0; r < 13; ++r) acc[r] = 0.f;
                unsigned p = e0;
                for (; p + 4 <= e1; p += 4) {
                    float4 cv[4];
#pragma unroll
                    for (int b = 0; b < 4; ++b) cv[b] = C2R[p + b];
                    float xv[4];
#pragma unroll
                    for (int b = 0; b < 4; ++b)
                        xv[b] = xp[__float_as_int(cv[b].w) * 32 + i];
#pragma unroll
                    for (int b = 0; b < 4; ++b) {
                        float a = ba0 + (cv[b].x * inv + 0.5f) * wa0 + (cv[b].y * inv + 0.5f) * wa1
                                      + (cv[b].z * inv + 0.5f) * wa2;
                        float hown = (l == 25) ? 1.f : fmaxf(a, 0.f);
#pragma unroll
                        for (int r = 0; r < 13; ++r)
                            acc[r] += __shfl(hown, 2 * r + hp, 64) * xv[b];
                    }
                }
                for (; p < e1; ++p) {
                    float4 cv = C2R[p];
                    float xv = xp[__float_as_int(cv.w) * 32 + i];
                    float a = ba0 + (cv.x * inv + 0.5f) * wa0 + (cv.y * inv + 0.5f) * wa1
                                  + (cv.z * inv + 0.5f) * wa2;
                    float hown = (l == 25) ? 1.f : fmaxf(a, 0.f);
#pragma unroll
                    for (int r = 0; r < 13; ++r)
                        acc[r] += __shfl(hown, 2 * r + hp, 64) * xv;
                }
                const float dinv = 1.f / fmaxf((float)(e1 - e0), 1.f);
#pragma unroll
                for (int r = 0; r < 13; ++r) As[row][r * 64 + l] = f2bf(acc[r] * dinv);
                As[row][832 + l] = f2bf((l < 32) ? xp[d * 32 + l] : (l == 32 ? 1.f : 0.f));
            } else {
#pragma unroll
                for (int r = 0; r < 13; ++r) As[row][r * 64 + l] = 0;
                As[row][832 + l] = 0;
            }
        }
        __syncthreads();
        // ---- phase 2: waves 0..3 MFMA the four 16-col quadrants; wave 4 aux ----
        if (w < 4) {
            f32x4 a4 = {0.f, 0.f, 0.f, 0.f};
#pragma unroll 4
            for (int s = 0; s < 28; ++s) {
                short8 av = *reinterpret_cast<const short8*>(&As[m][s * 32 + q * 8]);
                short8 bv = *reinterpret_cast<const short8*>(&W2T[(w * 16 + m) * 896 + s * 32 + q * 8]);
                a4 = __builtin_amdgcn_mfma_f32_16x16x32_bf16(av, bv, a4, 0, 0, 0);
            }
#pragma unroll
            for (int r = 0; r < 4; ++r) {
                const int row = base + q * 4 + r;
                if (row < C1n) {
                    const int c2 = cl2[row];
                    float v = elu(a4[r]);
                    atomicMax(&x3key[c2 * 64 + w * 16 + m], fkey(v));
                }
            }
        } else if (w == 4) {
            if (l < 16) {
                const int row = base + l;
                if (row < C1n) atomicMax(&b2max[cl2[row]], bpmax[row]);
            }
        }
        __syncthreads();
    }
}

// ---- two-stage batch reduction: LDS partials, then 1 global atomic/slot ----
__global__ __launch_bounds__(256) void gacc_kernel(
    const unsigned* __restrict__ x3key, const int* __restrict__ b2max,
    float* __restrict__ gsum, float* __restrict__ gcnt) {
    __shared__ float ls[Bb * 64];
    __shared__ float lc[Bb];
    const int t = threadIdx.x;
    for (int i = t; i < Bb * 64; i += 256) ls[i] = 0.f;
    if (t < Bb) lc[t] = 0.f;
    __syncthreads();
    const int o = t & 63;
    const int cs = t >> 6;
    for (int c = blockIdx.x * 4 + cs; c < C2n; c += gridDim.x * 4) {
        int b = b2max[c];
        unsigned k = x3key[c * 64 + o];
        float v = k ? funkey(k) : 0.f;
        atomicAdd(&ls[b * 64 + o], v);
        if (o == 0) atomicAdd(&lc[b], 1.f);
    }
    __syncthreads();
    for (int i = t; i < Bb * 64; i += 256) {
        float v = ls[i];
        if (v != 0.f) atomicAdd(&gsum[i], v);
    }
    if (t < Bb) {
        float v = lc[t];
        if (v != 0.f) atomicAdd(&gcnt[t], v);
    }
}

__global__ void head_kernel(const float* __restrict__ gsum, const float* __restrict__ gcnt,
                            const float* __restrict__ fc1w, const float* __restrict__ fc1b,
                            const float* __restrict__ fc2w, const float* __restrict__ fc2b,
                            float* __restrict__ out) {
    __shared__ float g[16 * 64];
    __shared__ float hb[16 * 128];
    __shared__ float lg[16 * 10];
    __shared__ float rowm[16];
    int t = threadIdx.x;
    for (int idx = t; idx < 16 * 64; idx += 256) {
        int b = idx >> 6;
        g[idx] = gsum[idx] / fmaxf(gcnt[b], 1.f);
    }
    __syncthreads();
    for (int idx = t; idx < 16 * 128; idx += 256) {
        int b = idx >> 7, j = idx & 127;
        float a = fc1b[j];
        for (int i = 0; i < 64; ++i) a += g[b * 64 + i] * fc1w[i * 128 + j];
        hb[idx] = elu(a);
    }
    __syncthreads();
    for (int idx = t; idx < 160; idx += 256) {
        int b = idx / 10, c = idx % 10;
        float a = fc2b[c];
        for (int i = 0; i < 128; ++i) a += hb[b * 128 + i] * fc2w[i * 10 + c];
        lg[idx] = a;
    }
    __syncthreads();
    if (t < 16) {
        float m = -1e30f;
        for (int c = 0; c < 10; ++c) m = fmaxf(m, lg[t * 10 + c]);
        float s = 0.f;
        for (int c = 0; c < 10; ++c) s += expf(lg[t * 10 + c] - m);
        rowm[t] = m + logf(s);
    }
    __syncthreads();
    for (int idx = t; idx < 160; idx += 256) out[idx] = lg[idx] - rowm[idx / 10];
}

extern "C" void kernel_launch(void* const* d_in, const int* in_sizes, int n_in,
                              void* d_out, int out_size, void* d_ws, size_t ws_size,
                              hipStream_t stream) {
    const float* x     = (const float*)d_in[0];
    const float* ea    = (const float*)d_in[1];
    const float* pos   = (const float*)d_in[2];
    const int*   ei    = (const int*)d_in[3];
    const int*   batch = (const int*)d_in[4];
    const int*   cl1   = (const int*)d_in[5];
    const int*   ei2   = (const int*)d_in[6];
    const int*   cl2   = (const int*)d_in[7];
    const float* w1a   = (const float*)d_in[8];
    const float* b1a   = (const float*)d_in[9];
    const float* w1b   = (const float*)d_in[10];
    const float* b1b   = (const float*)d_in[11];
    const float* root1 = (const float*)d_in[12];
    const float* bias1 = (const float*)d_in[13];
    const float* w2a   = (const float*)d_in[14];
    const float* b2a   = (const float*)d_in[15];
    const float* w2b   = (const float*)d_in[16];
    const float* b2b   = (const float*)d_in[17];
    const float* root2 = (const float*)d_in[18];
    const float* bias2 = (const float*)d_in[19];
    const float* fc1w  = (const float*)d_in[20];
    const float* fc1b  = (const float*)d_in[21];
    const float* fc2w  = (const float*)d_in[22];
    const float* fc2b  = (const float*)d_in[23];
    float* out = (float*)d_out;

    float* ws = (float*)d_ws;
    unsigned* xpkey  = (unsigned*)(ws + OFF_XPKEY);
    float*    possum = ws + OFF_POSSUM;
    float*    cntc1  = ws + OFF_CNTC1;
    int*      bpmax  = (int*)(ws + OFF_BPMAX);
    unsigned* x3key  = (unsigned*)(ws + OFF_X3KEY);
    int*      b2max  = (int*)(ws + OFF_B2MAX);
    float*    gsum   = ws + OFF_GSUM;
    float*    gcnt   = ws + OFF_GCNT;
    unsigned* maxabs = (unsigned*)(ws + OFF_MAXABS);
    unsigned* deg1   = (unsigned*)(ws + OFF_DEG1);
    unsigned* fill1  = (unsigned*)(ws + OFF_FILL1);
    unsigned* deg2   = (unsigned*)(ws + OFF_DEG2);
    unsigned* fill2  = (unsigned*)(ws + OFF_FILL2);
    unsigned* rp1    = (unsigned*)(ws + OFF_RP1);
    unsigned* rp2    = (unsigned*)(ws + OFF_RP2);
    float*    posp   = ws + OFF_POSP;
    float*    xp     = ws + OFF_XP;
    unsigned short* W1T = (unsigned short*)(ws + OFF_W1T);
    unsigned short* W2T = (unsigned short*)(ws + OFF_W2T);
    float4*   EA1R  = (float4*)(ws + OFF_EA1R);
    float4*   C2R   = (float4*)(ws + OFF_C2R);

    hipMemsetAsync(ws, 0, (size_t)ZERO_ELEMS * 4, stream);

    wt_kernel<<<252, 256, 0, stream>>>(w1b, b1b, root1, bias1, w2b, b2b, root2, bias2, W1T, W2T);
    hist_kernel<<<(Ee + E2n + 255) / 256, 256, 0, stream>>>(ei, ei2, deg1, deg2);
    scan_both<<<2, 1024, 0, stream>>>(deg1, rp1, deg2, rp2);
    scatter1<<<(Ee + 255) / 256, 256, 0, stream>>>(ea, ei, rp1, fill1, EA1R);
    g1conv1<<<1875, 256, 0, stream>>>(x, EA1R, rp1, w1a, b1a, W1T, pos, batch, cl1,
                                      xpkey, possum, cntc1, bpmax);
    pool1_final<<<(C1n * 32 + 255) / 256, 256, 0, stream>>>(xpkey, possum, cntc1, xp, posp);
    scatter2<<<(E2n + 255) / 256, 256, 0, stream>>>(posp, ei2, rp2, fill2, C2R, maxabs);
    g2conv2<<<938, 512, 0, stream>>>(xp, C2R, maxabs, rp2, w2a, b2a, W2T, cl2, bpmax,
                                     x3key, b2max);
    gacc_kernel<<<32, 256, 0, stream>>>(x3key, b2max, gsum, gcnt);
    head_kernel<<<1, 256, 0, stream>>>(gsum, gcnt, fc1w, fc1b, fc2w, fc2b, out);
}

// Round 8
// 340.346 us; speedup vs baseline: 1.1036x; 1.0255x over previous
//
#include <hip/hip_runtime.h>
#include <hip/hip_bf16.h>

#define Nn 30000
#define Ee 400000
#define C1n 15000
#define E2n 100000
#define C2n 7500
#define Bb 16

// ---- workspace layout (float/u32 element offsets) ----
// zeroed region:
#define OFF_XPKEY   0         // C1*32 u32
#define OFF_POSSUM  480000    // C1*3
#define OFF_CNTC1   525000    // C1
#define OFF_BPMAX   540000    // C1 i32
#define OFF_X3KEY   555000    // C2*64 u32
#define OFF_B2MAX   1035000   // C2 i32
#define OFF_GSUM    1042500   // B*64
#define OFF_GCNT    1043524   // B
#define OFF_MAXABS  1043540   // 1 u32 (pad to 1043544)
#define OFF_DEG1    1043544   // N u32
#define OFF_FILL1   1073544   // N u32
#define OFF_DEG2    1103544   // C1 u32
#define OFF_FILL2   1118544   // C1 u32
#define ZERO_ELEMS  1133544
// non-zeroed:
#define OFF_RP1     1133544   // N+1 u32 (pad 30004)
#define OFF_RP2     1163548   // C1+1 u32 (pad 15004)
#define OFF_POSP    1178552   // C1*3
#define OFF_XP      1223552   // C1*32
#define OFF_W1T     1703552   // 32*224 bf16 = 3584 floats (padded K: j=k*8+i)
#define OFF_W2T     1707136   // 64*896 bf16 = 28672 floats
#define OFF_EA1R    1735808   // E float4 (ea0,ea1,ea2,src_bits), dst-sorted
#define OFF_C2R     3335808   // E2 float4 (cart0,1,2,src_bits), dst-sorted
// total 3735808 floats ~ 15 MB

typedef __attribute__((ext_vector_type(8))) short short8;
typedef __attribute__((ext_vector_type(4))) float f32x4;

__device__ __forceinline__ unsigned fkey(float f) {
    unsigned u = __float_as_uint(f);
    return (u >> 31) ? ~u : (u | 0x80000000u);
}
__device__ __forceinline__ float funkey(unsigned k) {
    unsigned u = (k >> 31) ? (k ^ 0x80000000u) : ~k;
    return __uint_as_float(u);
}
__device__ __forceinline__ float elu(float a) { return a > 0.f ? a : expm1f(a); }

__device__ __forceinline__ unsigned short f2bf(float f) {
    unsigned u = __float_as_uint(f);
    unsigned lsb = (u >> 16) & 1u;
    u += 0x7fffu + lsb;  // round to nearest even
    return (unsigned short)(u >> 16);
}

// ==== CSR build: histogram (both graphs in one launch) ====
__global__ void hist_kernel(const int* __restrict__ ei, const int* __restrict__ ei2,
                            unsigned* __restrict__ deg1, unsigned* __restrict__ deg2) {
    int t = blockIdx.x * 256 + threadIdx.x;
    if (t < Ee) {
        atomicAdd(&deg1[ei[Ee + t]], 1u);
    } else if (t < Ee + E2n) {
        int e = t - Ee;
        atomicAdd(&deg2[ei2[E2n + e]], 1u);
    }
}

// single-block scans; block 0 -> graph1 (N), block 1 -> graph2 (C1)
__global__ __launch_bounds__(1024) void scan_both(
    const unsigned* __restrict__ deg1, unsigned* __restrict__ rp1,
    const unsigned* __restrict__ deg2, unsigned* __restrict__ rp2) {
    const unsigned* deg; unsigned* rp; int n;
    if (blockIdx.x == 0) { deg = deg1; rp = rp1; n = Nn; }
    else                 { deg = deg2; rp = rp2; n = C1n; }
    __shared__ unsigned ps[1024];
    const int t = threadIdx.x;
    const int chunk = (n + 1023) / 1024;
    const int lo = t * chunk;
    const int hi = (lo + chunk < n) ? lo + chunk : n;
    unsigned s = 0;
    for (int i = lo; i < hi; ++i) s += deg[i];
    ps[t] = s;
    __syncthreads();
    for (int off = 1; off < 1024; off <<= 1) {
        unsigned v = (t >= off) ? ps[t - off] : 0u;
        __syncthreads();
        ps[t] += v;
        __syncthreads();
    }
    unsigned run = (t > 0) ? ps[t - 1] : 0u;
    if (t == 0) rp[0] = 0u;
    for (int i = lo; i < hi; ++i) { run += deg[i]; rp[i + 1] = run; }
}

// ==== scatter1: edge attrs + src index into dst-sorted slots (16B payload) ====
__global__ void scatter1(const float* __restrict__ ea, const int* __restrict__ ei,
                         const unsigned* __restrict__ rp1, unsigned* __restrict__ fill1,
                         float4* __restrict__ EA1R) {
    int e = blockIdx.x * 256 + threadIdx.x;
    if (e >= Ee) return;
    int d = ei[Ee + e];
    unsigned p = rp1[d] + atomicAdd(&fill1[d], 1u);
    int src = ei[e];
    EA1R[p] = make_float4(ea[e * 3], ea[e * 3 + 1], ea[e * 3 + 2], __int_as_float(src));
}

// ==== precompute transposed bf16 weight panels (K-major per col) ====
// W1T: K=224, j=k*8+i padded layout. p<208: (k=p>>3,i=p&7) -> w1b/b1b (0 for i>=6);
//      208..213: root1; 214: bias1; 215..223: 0.
// W2T: K=896, j=k*32+i.
__global__ void wt_kernel(const float* __restrict__ w1b, const float* __restrict__ b1b,
                          const float* __restrict__ root1, const float* __restrict__ bias1,
                          const float* __restrict__ w2b, const float* __restrict__ b2b,
                          const float* __restrict__ root2, const float* __restrict__ bias2,
                          unsigned short* __restrict__ W1T, unsigned short* __restrict__ W2T) {
    int t = blockIdx.x * 256 + threadIdx.x;
    if (t < 32 * 224) {
        int col = t / 224, p = t % 224;
        float v = 0.f;
        if (p < 208) {
            int k = p >> 3, i = p & 7;
            if (i < 6) v = (k < 25) ? w1b[k * 192 + i * 32 + col] : b1b[i * 32 + col];
        }
        else if (p < 214)  { v = root1[(p - 208) * 32 + col]; }
        else if (p == 214) { v = bias1[col]; }
        W1T[t] = f2bf(v);
    } else {
        int u = t - 32 * 224;
        if (u < 64 * 896) {
            int col = u / 896, p = u % 896;
            float v;
            if (p < 800)       { int k = p / 32, i = p % 32; v = w2b[k * 2048 + i * 64 + col]; }
            else if (p < 832)  { int i = p - 800; v = b2b[i * 64 + col]; }
            else if (p < 864)  { v = root2[(p - 832) * 64 + col]; }
            else if (p == 864) { v = bias2[col]; }
            else v = 0.f;
            W2T[u] = f2bf(v);
        }
    }
}

// ==== fused g1 + conv1 + pool1, padded-K layout (1 gather/edge), masked
//      batch-4 edge loop (no serial tail). ====
__global__ __launch_bounds__(256, 8) void g1conv1(
    const float* __restrict__ x, const float4* __restrict__ EA1R,
    const unsigned* __restrict__ rp1,
    const float* __restrict__ w1a, const float* __restrict__ b1a,
    const unsigned short* __restrict__ W1T,
    const float* __restrict__ pos, const int* __restrict__ batch, const int* __restrict__ cl1,
    unsigned* __restrict__ xpkey, float* __restrict__ possum,
    float* __restrict__ cntc1, int* __restrict__ bpmax) {
    __shared__ unsigned short As[16][232];  // bf16; stride 464B -> 2-way banks on b128 reads
    const int tid = threadIdx.x;
    const int w = tid >> 6;   // wave 0..3
    const int l = tid & 63;
    const int m = l & 15, q = l >> 4;
    const int i8 = l & 7;          // lane's x column (all r), i8>=6 -> zero pad
    const int kq = l >> 3;         // k offset within each r-block
    float wa0 = 0.f, wa1 = 0.f, wa2 = 0.f, ba0 = 0.f;
    if (l < 25) { wa0 = w1a[l]; wa1 = w1a[25 + l]; wa2 = w1a[50 + l]; ba0 = b1a[l]; }
    const int ntiles = Nn / 16;   // 1875
    for (int tile = blockIdx.x; tile < ntiles; tile += gridDim.x) {
        const int base = tile * 16;
        // ---- phase 1: each wave gathers 4 dst rows; masked batch-4 ----
#pragma unroll
        for (int s4 = 0; s4 < 4; ++s4) {
            const int row = w * 4 + s4;
            const int d = base + row;
            const unsigned e0 = rp1[d], e1 = rp1[d + 1];
            float acc0 = 0.f, acc1 = 0.f, acc2 = 0.f, acc3 = 0.f;
            for (unsigned p = e0; p < e1; p += 4) {
                float4 ev[4];
                float xm[4];
#pragma unroll
                for (int b = 0; b < 4; ++b) {
                    const unsigned pp = (p + b < e1) ? p + b : e1 - 1;
                    ev[b] = EA1R[pp];
                }
#pragma unroll
                for (int b = 0; b < 4; ++b) {
                    const int sb = __float_as_int(ev[b].w) * 6;
                    xm[b] = (i8 < 6 && p + b < e1) ? x[sb + i8] : 0.f;  // masked: tail edges add 0
                }
#pragma unroll
                for (int b = 0; b < 4; ++b) {
                    float a = ba0 + ev[b].x * wa0 + ev[b].y * wa1 + ev[b].z * wa2;
                    float hown = (l == 25) ? 1.f : fmaxf(a, 0.f);
                    acc0 += __shfl(hown, kq, 64) * xm[b];
                    acc1 += __shfl(hown, 8 + kq, 64) * xm[b];
                    acc2 += __shfl(hown, 16 + kq, 64) * xm[b];
                    acc3 += __shfl(hown, 24 + kq, 64) * xm[b];  // k=24,25 live in lanes l<16
                }
            }
            const float dinv = 1.f / fmaxf((float)(e1 - e0), 1.f);
            As[row][l] = f2bf(acc0 * dinv);          // j 0..63   (k 0..7)
            As[row][64 + l] = f2bf(acc1 * dinv);     // j 64..127 (k 8..15)
            As[row][128 + l] = f2bf(acc2 * dinv);    // j 128..191(k 16..23)
            if (l < 16) {
                As[row][192 + l] = f2bf(acc3 * dinv);  // j 192..207 (k 24..25)
                float tail;
                if (l < 6)       tail = x[d * 6 + l];   // root slot
                else if (l == 6) tail = 1.f;            // bias slot (j=214)
                else             tail = 0.f;
                As[row][208 + l] = f2bf(tail);
            }
        }
        __syncthreads();
        // ---- phase 2: waves 0,1 MFMA the two 16-col quadrants; wave 2 pool aux ----
        if (w < 2) {
            f32x4 acc = {0.f, 0.f, 0.f, 0.f};
#pragma unroll
            for (int s = 0; s < 7; ++s) {
                short8 av = *reinterpret_cast<const short8*>(&As[m][s * 32 + q * 8]);
                short8 bv = *reinterpret_cast<const short8*>(&W1T[(w * 16 + m) * 224 + s * 32 + q * 8]);
                acc = __builtin_amdgcn_mfma_f32_16x16x32_bf16(av, bv, acc, 0, 0, 0);
            }
#pragma unroll
            for (int r = 0; r < 4; ++r) {
                const int row = base + q * 4 + r;
                const int c = cl1[row];
                float v = elu(acc[r]);
                atomicMax(&xpkey[c * 32 + w * 16 + m], fkey(v));
            }
        } else if (w == 2) {
            if (l < 16) {
                const int row = base + l;
                const int c = cl1[row];
#pragma unroll
                for (int j = 0; j < 3; ++j) atomicAdd(&possum[c * 3 + j], pos[row * 3 + j]);
                atomicAdd(&cntc1[c], 1.f);
                atomicMax(&bpmax[c], batch[row]);
            }
        }
        __syncthreads();
    }
}

__global__ void pool1_final(const unsigned* __restrict__ xpkey, const float* __restrict__ possum,
                            const float* __restrict__ cntc1, float* __restrict__ xp,
                            float* __restrict__ posp) {
    int t = blockIdx.x * 256 + threadIdx.x;
    if (t >= C1n * 32) return;
    int c = t >> 5, o = t & 31;
    unsigned k = xpkey[t];
    xp[t] = k ? funkey(k) : 0.f;
    if (o < 3) posp[c * 3 + o] = possum[c * 3 + o] / fmaxf(cntc1[c], 1.f);
}

// ==== scatter2 (+fused cart): cart from posp, src index, dst-sorted 16B payload ====
__global__ void scatter2(const float* __restrict__ posp, const int* __restrict__ ei2,
                         const unsigned* __restrict__ rp2, unsigned* __restrict__ fill2,
                         float4* __restrict__ C2R, unsigned* __restrict__ maxabs) {
    int e = blockIdx.x * 256 + threadIdx.x;
    float mx = 0.f;
    if (e < E2n) {
        int s = ei2[e], d = ei2[E2n + e];
        float c0 = posp[s * 3]     - posp[d * 3];
        float c1 = posp[s * 3 + 1] - posp[d * 3 + 1];
        float c2 = posp[s * 3 + 2] - posp[d * 3 + 2];
        mx = fmaxf(fmaxf(fabsf(c0), fabsf(c1)), fabsf(c2));
        unsigned p = rp2[d] + atomicAdd(&fill2[d], 1u);
        C2R[p] = make_float4(c0, c1, c2, __int_as_float(s));
    }
#pragma unroll
    for (int off = 32; off > 0; off >>= 1) mx = fmaxf(mx, __shfl_xor(mx, off));
    if ((threadIdx.x & 63) == 0) atomicMax(maxabs, __float_as_uint(mx));
}

// ==== fused g2 + conv2 + pool2: 256-thread blocks. Phase 1: each of 4 waves
//      gathers 4 rows (masked batch-4, no serial tail). Phase 2: EVERY wave
//      MFMAs one 16x16 quadrant — no idle waves at the barrier. ====
__global__ __launch_bounds__(256, 5) void g2conv2(
    const float* __restrict__ xp, const float4* __restrict__ C2R,
    const unsigned* __restrict__ maxabs, const unsigned* __restrict__ rp2,
    const float* __restrict__ w2a, const float* __restrict__ b2a,
    const unsigned short* __restrict__ W2T,
    const int* __restrict__ cl2, const int* __restrict__ bpmax,
    unsigned* __restrict__ x3key, int* __restrict__ b2max) {
    __shared__ unsigned short As[16][904];  // 28.9 KB -> 5 blocks/CU
    const int tid = threadIdx.x;
    const int w = tid >> 6;   // wave 0..3
    const int l = tid & 63;
    const int m = l & 15, q = l >> 4;
    const int i = l & 31, hp = l >> 5;
    float wa0 = 0.f, wa1 = 0.f, wa2 = 0.f, ba0 = 0.f;
    if (l < 25) { wa0 = w2a[l]; wa1 = w2a[25 + l]; wa2 = w2a[50 + l]; ba0 = b2a[l]; }
    const float inv = 0.5f / __uint_as_float(maxabs[0]);
    const int ntiles = (C1n + 15) / 16;   // 938
    for (int tile = blockIdx.x; tile < ntiles; tile += gridDim.x) {
        const int base = tile * 16;
        // ---- phase 1: each wave gathers 4 dst rows; masked batch-4 ----
#pragma unroll
        for (int s4 = 0; s4 < 4; ++s4) {
            const int row = w * 4 + s4;
            const int d = base + row;
            if (d < C1n) {
                const unsigned e0 = rp2[d], e1 = rp2[d + 1];
                float acc[13];
#pragma unroll
                for (int r = 0; r < 13; ++r) acc[r] = 0.f;
                for (unsigned p = e0; p < e1; p += 4) {
                    float4 cv[4];
                    float xv[4];
#pragma unroll
                    for (int b = 0; b < 4; ++b) {
                        const unsigned pp = (p + b < e1) ? p + b : e1 - 1;
                        cv[b] = C2R[pp];
                    }
#pragma unroll
                    for (int b = 0; b < 4; ++b)
                        xv[b] = (p + b < e1) ? xp[__float_as_int(cv[b].w) * 32 + i] : 0.f;
#pragma unroll
                    for (int b = 0; b < 4; ++b) {
                        float a = ba0 + (cv[b].x * inv + 0.5f) * wa0 + (cv[b].y * inv + 0.5f) * wa1
                                      + (cv[b].z * inv + 0.5f) * wa2;
                        float hown = (l == 25) ? 1.f : fmaxf(a, 0.f);
#pragma unroll
                        for (int r = 0; r < 13; ++r)
                            acc[r] += __shfl(hown, 2 * r + hp, 64) * xv[b];
                    }
                }
                const float dinv = 1.f / fmaxf((float)(e1 - e0), 1.f);
#pragma unroll
                for (int r = 0; r < 13; ++r) As[row][r * 64 + l] = f2bf(acc[r] * dinv);
                As[row][832 + l] = f2bf((l < 32) ? xp[d * 32 + l] : (l == 32 ? 1.f : 0.f));
                if (l == 0) atomicMax(&b2max[cl2[d]], bpmax[d]);   // aux fused here
            } else {
#pragma unroll
                for (int r = 0; r < 13; ++r) As[row][r * 64 + l] = 0;
                As[row][832 + l] = 0;
            }
        }
        __syncthreads();
        // ---- phase 2: wave w MFMAs quadrant w (all 4 waves busy) ----
        {
            f32x4 a4 = {0.f, 0.f, 0.f, 0.f};
#pragma unroll 4
            for (int s = 0; s < 28; ++s) {
                short8 av = *reinterpret_cast<const short8*>(&As[m][s * 32 + q * 8]);
                short8 bv = *reinterpret_cast<const short8*>(&W2T[(w * 16 + m) * 896 + s * 32 + q * 8]);
                a4 = __builtin_amdgcn_mfma_f32_16x16x32_bf16(av, bv, a4, 0, 0, 0);
            }
#pragma unroll
            for (int r = 0; r < 4; ++r) {
                const int row = base + q * 4 + r;
                if (row < C1n) {
                    const int c2 = cl2[row];
                    float v = elu(a4[r]);
                    atomicMax(&x3key[c2 * 64 + w * 16 + m], fkey(v));
                }
            }
        }
        __syncthreads();
    }
}

// ---- two-stage batch reduction: LDS partials, then 1 global atomic/slot ----
__global__ __launch_bounds__(256) void gacc_kernel(
    const unsigned* __restrict__ x3key, const int* __restrict__ b2max,
    float* __restrict__ gsum, float* __restrict__ gcnt) {
    __shared__ float ls[Bb * 64];
    __shared__ float lc[Bb];
    const int t = threadIdx.x;
    for (int i = t; i < Bb * 64; i += 256) ls[i] = 0.f;
    if (t < Bb) lc[t] = 0.f;
    __syncthreads();
    const int o = t & 63;
    const int cs = t >> 6;
    for (int c = blockIdx.x * 4 + cs; c < C2n; c += gridDim.x * 4) {
        int b = b2max[c];
        unsigned k = x3key[c * 64 + o];
        float v = k ? funkey(k) : 0.f;
        atomicAdd(&ls[b * 64 + o], v);
        if (o == 0) atomicAdd(&lc[b], 1.f);
    }
    __syncthreads();
    for (int i = t; i < Bb * 64; i += 256) {
        float v = ls[i];
        if (v != 0.f) atomicAdd(&gsum[i], v);
    }
    if (t < Bb) {
        float v = lc[t];
        if (v != 0.f) atomicAdd(&gcnt[t], v);
    }
}

__global__ void head_kernel(const float* __restrict__ gsum, const float* __restrict__ gcnt,
                            const float* __restrict__ fc1w, const float* __restrict__ fc1b,
                            const float* __restrict__ fc2w, const float* __restrict__ fc2b,
                            float* __restrict__ out) {
    __shared__ float g[16 * 64];
    __shared__ float hb[16 * 128];
    __shared__ float lg[16 * 10];
    __shared__ float rowm[16];
    int t = threadIdx.x;
    for (int idx = t; idx < 16 * 64; idx += 256) {
        int b = idx >> 6;
        g[idx] = gsum[idx] / fmaxf(gcnt[b], 1.f);
    }
    __syncthreads();
    for (int idx = t; idx < 16 * 128; idx += 256) {
        int b = idx >> 7, j = idx & 127;
        float a = fc1b[j];
        for (int i = 0; i < 64; ++i) a += g[b * 64 + i] * fc1w[i * 128 + j];
        hb[idx] = elu(a);
    }
    __syncthreads();
    for (int idx = t; idx < 160; idx += 256) {
        int b = idx / 10, c = idx % 10;
        float a = fc2b[c];
        for (int i = 0; i < 128; ++i) a += hb[b * 128 + i] * fc2w[i * 10 + c];
        lg[idx] = a;
    }
    __syncthreads();
    if (t < 16) {
        float m = -1e30f;
        for (int c = 0; c < 10; ++c) m = fmaxf(m, lg[t * 10 + c]);
        float s = 0.f;
        for (int c = 0; c < 10; ++c) s += expf(lg[t * 10 + c] - m);
        rowm[t] = m + logf(s);
    }
    __syncthreads();
    for (int idx = t; idx < 160; idx += 256) out[idx] = lg[idx] - rowm[idx / 10];
}

extern "C" void kernel_launch(void* const* d_in, const int* in_sizes, int n_in,
                              void* d_out, int out_size, void* d_ws, size_t ws_size,
                              hipStream_t stream) {
    const float* x     = (const float*)d_in[0];
    const float* ea    = (const float*)d_in[1];
    const float* pos   = (const float*)d_in[2];
    const int*   ei    = (const int*)d_in[3];
    const int*   batch = (const int*)d_in[4];
    const int*   cl1   = (const int*)d_in[5];
    const int*   ei2   = (const int*)d_in[6];
    const int*   cl2   = (const int*)d_in[7];
    const float* w1a   = (const float*)d_in[8];
    const float* b1a   = (const float*)d_in[9];
    const float* w1b   = (const float*)d_in[10];
    const float* b1b   = (const float*)d_in[11];
    const float* root1 = (const float*)d_in[12];
    const float* bias1 = (const float*)d_in[13];
    const float* w2a   = (const float*)d_in[14];
    const float* b2a   = (const float*)d_in[15];
    const float* w2b   = (const float*)d_in[16];
    const float* b2b   = (const float*)d_in[17];
    const float* root2 = (const float*)d_in[18];
    const float* bias2 = (const float*)d_in[19];
    const float* fc1w  = (const float*)d_in[20];
    const float* fc1b  = (const float*)d_in[21];
    const float* fc2w  = (const float*)d_in[22];
    const float* fc2b  = (const float*)d_in[23];
    float* out = (float*)d_out;

    float* ws = (float*)d_ws;
    unsigned* xpkey  = (unsigned*)(ws + OFF_XPKEY);
    float*    possum = ws + OFF_POSSUM;
    float*    cntc1  = ws + OFF_CNTC1;
    int*      bpmax  = (int*)(ws + OFF_BPMAX);
    unsigned* x3key  = (unsigned*)(ws + OFF_X3KEY);
    int*      b2max  = (int*)(ws + OFF_B2MAX);
    float*    gsum   = ws + OFF_GSUM;
    float*    gcnt   = ws + OFF_GCNT;
    unsigned* maxabs = (unsigned*)(ws + OFF_MAXABS);
    unsigned* deg1   = (unsigned*)(ws + OFF_DEG1);
    unsigned* fill1  = (unsigned*)(ws + OFF_FILL1);
    unsigned* deg2   = (unsigned*)(ws + OFF_DEG2);
    unsigned* fill2  = (unsigned*)(ws + OFF_FILL2);
    unsigned* rp1    = (unsigned*)(ws + OFF_RP1);
    unsigned* rp2    = (unsigned*)(ws + OFF_RP2);
    float*    posp   = ws + OFF_POSP;
    float*    xp     = ws + OFF_XP;
    unsigned short* W1T = (unsigned short*)(ws + OFF_W1T);
    unsigned short* W2T = (unsigned short*)(ws + OFF_W2T);
    float4*   EA1R  = (float4*)(ws + OFF_EA1R);
    float4*   C2R   = (float4*)(ws + OFF_C2R);

    hipMemsetAsync(ws, 0, (size_t)ZERO_ELEMS * 4, stream);

    wt_kernel<<<252, 256, 0, stream>>>(w1b, b1b, root1, bias1, w2b, b2b, root2, bias2, W1T, W2T);
    hist_kernel<<<(Ee + E2n + 255) / 256, 256, 0, stream>>>(ei, ei2, deg1, deg2);
    scan_both<<<2, 1024, 0, stream>>>(deg1, rp1, deg2, rp2);
    scatter1<<<(Ee + 255) / 256, 256, 0, stream>>>(ea, ei, rp1, fill1, EA1R);
    g1conv1<<<1875, 256, 0, stream>>>(x, EA1R, rp1, w1a, b1a, W1T, pos, batch, cl1,
                                      xpkey, possum, cntc1, bpmax);
    pool1_final<<<(C1n * 32 + 255) / 256, 256, 0, stream>>>(xpkey, possum, cntc1, xp, posp);
    scatter2<<<(E2n + 255) / 256, 256, 0, stream>>>(posp, ei2, rp2, fill2, C2R, maxabs);
    g2conv2<<<938, 256, 0, stream>>>(xp, C2R, maxabs, rp2, w2a, b2a, W2T, cl2, bpmax,
                                     x3key, b2max);
    gacc_kernel<<<32, 256, 0, stream>>>(x3key, b2max, gsum, gcnt);
    head_kernel<<<1, 256, 0, stream>>>(gsum, gcnt, fc1w, fc1b, fc2w, fc2b, out);
}

// Round 9
// 334.655 us; speedup vs baseline: 1.1224x; 1.0170x over previous
//
#include <hip/hip_runtime.h>
#include <hip/hip_bf16.h>

#define Nn 30000
#define Ee 400000
#define C1n 15000
#define E2n 100000
#define C2n 7500
#define Bb 16

// ---- workspace layout (float/u32 element offsets) ----
// zeroed region:
#define OFF_XPKEY   0         // C1*32 u32
#define OFF_POSSUM  480000    // C1*3
#define OFF_CNTC1   525000    // C1
#define OFF_BPMAX   540000    // C1 i32
#define OFF_X3KEY   555000    // C2*64 u32
#define OFF_B2MAX   1035000   // C2 i32
#define OFF_GSUM    1042500   // B*64
#define OFF_GCNT    1043524   // B
#define OFF_MAXABS  1043540   // 1 u32 (pad to 1043544)
#define OFF_DEG1    1043544   // N u32
#define OFF_FILL1   1073544   // N u32
#define OFF_DEG2    1103544   // C1 u32
#define OFF_FILL2   1118544   // C1 u32
#define ZERO_ELEMS  1133544
// non-zeroed:
#define OFF_RP1     1133544   // N+1 u32 (pad 30004)
#define OFF_RP2     1163548   // C1+1 u32 (pad 15004)
#define OFF_POSP    1178552   // C1*3
#define OFF_XP      1223552   // C1*32
#define OFF_W1T     1703552   // 32*224 bf16 = 3584 floats (padded K: j=k*8+i)
#define OFF_W2T     1707136   // 64*896 bf16 = 28672 floats
#define OFF_EA1R    1735808   // E float4 (ea0,ea1,ea2,-), dst-sorted
#define OFF_C2R     3335808   // E2 float4 (cart0,1,2,-), dst-sorted
#define OFF_X1R     3735808   // E*8 floats: x[src][0..5],0,0 dst-sorted (linear in g1)
#define OFF_XP2R    6935808   // E2*32 floats: xp[src] dst-sorted (linear in g2)
// total 10135808 floats ~ 40.5 MB

typedef __attribute__((ext_vector_type(8))) short short8;
typedef __attribute__((ext_vector_type(4))) float f32x4;

__device__ __forceinline__ unsigned fkey(float f) {
    unsigned u = __float_as_uint(f);
    return (u >> 31) ? ~u : (u | 0x80000000u);
}
__device__ __forceinline__ float funkey(unsigned k) {
    unsigned u = (k >> 31) ? (k ^ 0x80000000u) : ~k;
    return __uint_as_float(u);
}
__device__ __forceinline__ float elu(float a) { return a > 0.f ? a : expm1f(a); }

__device__ __forceinline__ unsigned short f2bf(float f) {
    unsigned u = __float_as_uint(f);
    unsigned lsb = (u >> 16) & 1u;
    u += 0x7fffu + lsb;  // round to nearest even
    return (unsigned short)(u >> 16);
}

// ==== CSR build: histogram (both graphs in one launch) ====
__global__ void hist_kernel(const int* __restrict__ ei, const int* __restrict__ ei2,
                            unsigned* __restrict__ deg1, unsigned* __restrict__ deg2) {
    int t = blockIdx.x * 256 + threadIdx.x;
    if (t < Ee) {
        atomicAdd(&deg1[ei[Ee + t]], 1u);
    } else if (t < Ee + E2n) {
        int e = t - Ee;
        atomicAdd(&deg2[ei2[E2n + e]], 1u);
    }
}

// single-block scans; block 0 -> graph1 (N), block 1 -> graph2 (C1)
__global__ __launch_bounds__(1024) void scan_both(
    const unsigned* __restrict__ deg1, unsigned* __restrict__ rp1,
    const unsigned* __restrict__ deg2, unsigned* __restrict__ rp2) {
    const unsigned* deg; unsigned* rp; int n;
    if (blockIdx.x == 0) { deg = deg1; rp = rp1; n = Nn; }
    else                 { deg = deg2; rp = rp2; n = C1n; }
    __shared__ unsigned ps[1024];
    const int t = threadIdx.x;
    const int chunk = (n + 1023) / 1024;
    const int lo = t * chunk;
    const int hi = (lo + chunk < n) ? lo + chunk : n;
    unsigned s = 0;
    for (int i = lo; i < hi; ++i) s += deg[i];
    ps[t] = s;
    __syncthreads();
    for (int off = 1; off < 1024; off <<= 1) {
        unsigned v = (t >= off) ? ps[t - off] : 0u;
        __syncthreads();
        ps[t] += v;
        __syncthreads();
    }
    unsigned run = (t > 0) ? ps[t - 1] : 0u;
    if (t == 0) rp[0] = 0u;
    for (int i = lo; i < hi; ++i) { run += deg[i]; rp[i + 1] = run; }
}

// ==== scatter1: edge attrs AND pre-gathered x[src] into dst-sorted slots ====
// The x gather lives here (edge-parallel, latency-tolerant); g1conv1 then
// reads only linearly-addressed streams.
__global__ void scatter1(const float* __restrict__ x, const float* __restrict__ ea,
                         const int* __restrict__ ei,
                         const unsigned* __restrict__ rp1, unsigned* __restrict__ fill1,
                         float4* __restrict__ EA1R, float4* __restrict__ X1R) {
    int e = blockIdx.x * 256 + threadIdx.x;
    if (e >= Ee) return;
    int d = ei[Ee + e];
    unsigned p = rp1[d] + atomicAdd(&fill1[d], 1u);
    int src = ei[e];
    EA1R[p] = make_float4(ea[e * 3], ea[e * 3 + 1], ea[e * 3 + 2], 0.f);
    const float* xs = x + (size_t)src * 6;
    X1R[p * 2]     = make_float4(xs[0], xs[1], xs[2], xs[3]);
    X1R[p * 2 + 1] = make_float4(xs[4], xs[5], 0.f, 0.f);   // zero pad i=6,7
}

// ==== precompute transposed bf16 weight panels (K-major per col) ====
// W1T: K=224, j=k*8+i padded layout. p<208: (k=p>>3,i=p&7) -> w1b/b1b (0 for i>=6);
//      208..213: root1; 214: bias1; 215..223: 0.
// W2T: K=896, j=k*32+i.
__global__ void wt_kernel(const float* __restrict__ w1b, const float* __restrict__ b1b,
                          const float* __restrict__ root1, const float* __restrict__ bias1,
                          const float* __restrict__ w2b, const float* __restrict__ b2b,
                          const float* __restrict__ root2, const float* __restrict__ bias2,
                          unsigned short* __restrict__ W1T, unsigned short* __restrict__ W2T) {
    int t = blockIdx.x * 256 + threadIdx.x;
    if (t < 32 * 224) {
        int col = t / 224, p = t % 224;
        float v = 0.f;
        if (p < 208) {
            int k = p >> 3, i = p & 7;
            if (i < 6) v = (k < 25) ? w1b[k * 192 + i * 32 + col] : b1b[i * 32 + col];
        }
        else if (p < 214)  { v = root1[(p - 208) * 32 + col]; }
        else if (p == 214) { v = bias1[col]; }
        W1T[t] = f2bf(v);
    } else {
        int u = t - 32 * 224;
        if (u < 64 * 896) {
            int col = u / 896, p = u % 896;
            float v;
            if (p < 800)       { int k = p / 32, i = p % 32; v = w2b[k * 2048 + i * 64 + col]; }
            else if (p < 832)  { int i = p - 800; v = b2b[i * 64 + col]; }
            else if (p < 864)  { v = root2[(p - 832) * 64 + col]; }
            else if (p == 864) { v = bias2[col]; }
            else v = 0.f;
            W2T[u] = f2bf(v);
        }
    }
}

// ==== fused g1 + conv1 + pool1, padded-K layout; ALL phase-1 loads are linear
//      in the CSR slot index -> 4 ev + 4 xm loads issue together, one wait,
//      zero dependent chains. ====
__global__ __launch_bounds__(256, 8) void g1conv1(
    const float4* __restrict__ EA1R, const float* __restrict__ X1Rf,
    const float* __restrict__ x, const unsigned* __restrict__ rp1,
    const float* __restrict__ w1a, const float* __restrict__ b1a,
    const unsigned short* __restrict__ W1T,
    const float* __restrict__ pos, const int* __restrict__ batch, const int* __restrict__ cl1,
    unsigned* __restrict__ xpkey, float* __restrict__ possum,
    float* __restrict__ cntc1, int* __restrict__ bpmax) {
    __shared__ unsigned short As[16][232];  // bf16; stride 464B -> 2-way banks on b128 reads
    const int tid = threadIdx.x;
    const int w = tid >> 6;   // wave 0..3
    const int l = tid & 63;
    const int m = l & 15, q = l >> 4;
    const int i8 = l & 7;          // lane's x column (pad rows make i8=6,7 read 0)
    const int kq = l >> 3;         // k offset within each r-block
    float wa0 = 0.f, wa1 = 0.f, wa2 = 0.f, ba0 = 0.f;
    if (l < 25) { wa0 = w1a[l]; wa1 = w1a[25 + l]; wa2 = w1a[50 + l]; ba0 = b1a[l]; }
    const int ntiles = Nn / 16;   // 1875
    for (int tile = blockIdx.x; tile < ntiles; tile += gridDim.x) {
        const int base = tile * 16;
        // ---- phase 1: each wave gathers 4 dst rows; masked batch-4, linear loads ----
#pragma unroll
        for (int s4 = 0; s4 < 4; ++s4) {
            const int row = w * 4 + s4;
            const int d = base + row;
            const unsigned e0 = rp1[d], e1 = rp1[d + 1];
            float acc0 = 0.f, acc1 = 0.f, acc2 = 0.f, acc3 = 0.f;
            for (unsigned p = e0; p < e1; p += 4) {
                float4 ev[4];
                float xm[4];
#pragma unroll
                for (int b = 0; b < 4; ++b) {
                    const unsigned pp = (p + b < e1) ? p + b : e1 - 1;
                    ev[b] = EA1R[pp];                    // linear
                    float xv = X1Rf[(size_t)pp * 8 + i8];  // linear, independent of ev
                    xm[b] = (p + b < e1) ? xv : 0.f;     // mask tail edges
                }
#pragma unroll
                for (int b = 0; b < 4; ++b) {
                    float a = ba0 + ev[b].x * wa0 + ev[b].y * wa1 + ev[b].z * wa2;
                    float hown = (l == 25) ? 1.f : fmaxf(a, 0.f);
                    acc0 += __shfl(hown, kq, 64) * xm[b];
                    acc1 += __shfl(hown, 8 + kq, 64) * xm[b];
                    acc2 += __shfl(hown, 16 + kq, 64) * xm[b];
                    acc3 += __shfl(hown, 24 + kq, 64) * xm[b];  // k=24,25 live in lanes l<16
                }
            }
            const float dinv = 1.f / fmaxf((float)(e1 - e0), 1.f);
            As[row][l] = f2bf(acc0 * dinv);          // j 0..63   (k 0..7)
            As[row][64 + l] = f2bf(acc1 * dinv);     // j 64..127 (k 8..15)
            As[row][128 + l] = f2bf(acc2 * dinv);    // j 128..191(k 16..23)
            if (l < 16) {
                As[row][192 + l] = f2bf(acc3 * dinv);  // j 192..207 (k 24..25)
                float tail;
                if (l < 6)       tail = x[d * 6 + l];   // root slot
                else if (l == 6) tail = 1.f;            // bias slot (j=214)
                else             tail = 0.f;
                As[row][208 + l] = f2bf(tail);
            }
        }
        __syncthreads();
        // ---- phase 2: waves 0,1 MFMA the two 16-col quadrants; wave 2 pool aux ----
        if (w < 2) {
            f32x4 acc = {0.f, 0.f, 0.f, 0.f};
#pragma unroll
            for (int s = 0; s < 7; ++s) {
                short8 av = *reinterpret_cast<const short8*>(&As[m][s * 32 + q * 8]);
                short8 bv = *reinterpret_cast<const short8*>(&W1T[(w * 16 + m) * 224 + s * 32 + q * 8]);
                acc = __builtin_amdgcn_mfma_f32_16x16x32_bf16(av, bv, acc, 0, 0, 0);
            }
#pragma unroll
            for (int r = 0; r < 4; ++r) {
                const int row = base + q * 4 + r;
                const int c = cl1[row];
                float v = elu(acc[r]);
                atomicMax(&xpkey[c * 32 + w * 16 + m], fkey(v));
            }
        } else if (w == 2) {
            if (l < 16) {
                const int row = base + l;
                const int c = cl1[row];
#pragma unroll
                for (int j = 0; j < 3; ++j) atomicAdd(&possum[c * 3 + j], pos[row * 3 + j]);
                atomicAdd(&cntc1[c], 1.f);
                atomicMax(&bpmax[c], batch[row]);
            }
        }
        __syncthreads();
    }
}

__global__ void pool1_final(const unsigned* __restrict__ xpkey, const float* __restrict__ possum,
                            const float* __restrict__ cntc1, float* __restrict__ xp,
                            float* __restrict__ posp) {
    int t = blockIdx.x * 256 + threadIdx.x;
    if (t >= C1n * 32) return;
    int c = t >> 5, o = t & 31;
    unsigned k = xpkey[t];
    xp[t] = k ? funkey(k) : 0.f;
    if (o < 3) posp[c * 3 + o] = possum[c * 3 + o] / fmaxf(cntc1[c], 1.f);
}

// ==== scatter2 (+fused cart + xp pre-gather): dst-sorted payloads ====
__global__ void scatter2(const float* __restrict__ posp, const float* __restrict__ xp,
                         const int* __restrict__ ei2,
                         const unsigned* __restrict__ rp2, unsigned* __restrict__ fill2,
                         float4* __restrict__ C2R, float4* __restrict__ XP2R,
                         unsigned* __restrict__ maxabs) {
    int e = blockIdx.x * 256 + threadIdx.x;
    float mx = 0.f;
    if (e < E2n) {
        int s = ei2[e], d = ei2[E2n + e];
        float c0 = posp[s * 3]     - posp[d * 3];
        float c1 = posp[s * 3 + 1] - posp[d * 3 + 1];
        float c2 = posp[s * 3 + 2] - posp[d * 3 + 2];
        mx = fmaxf(fmaxf(fabsf(c0), fabsf(c1)), fabsf(c2));
        unsigned p = rp2[d] + atomicAdd(&fill2[d], 1u);
        C2R[p] = make_float4(c0, c1, c2, 0.f);
        const float4* xs = reinterpret_cast<const float4*>(xp + (size_t)s * 32);
        float4* xd = XP2R + (size_t)p * 8;
#pragma unroll
        for (int j = 0; j < 8; ++j) xd[j] = xs[j];
    }
#pragma unroll
    for (int off = 32; off > 0; off >>= 1) mx = fmaxf(mx, __shfl_xor(mx, off));
    if ((threadIdx.x & 63) == 0) atomicMax(maxabs, __float_as_uint(mx));
}

// ==== fused g2 + conv2 + pool2: 256-thread blocks; phase-1 loads all linear
//      in CSR slot (C2R + XP2R), phase 2 all 4 waves MFMA. ====
__global__ __launch_bounds__(256, 5) void g2conv2(
    const float4* __restrict__ C2R, const float* __restrict__ XP2Rf,
    const float* __restrict__ xp,
    const unsigned* __restrict__ maxabs, const unsigned* __restrict__ rp2,
    const float* __restrict__ w2a, const float* __restrict__ b2a,
    const unsigned short* __restrict__ W2T,
    const int* __restrict__ cl2, const int* __restrict__ bpmax,
    unsigned* __restrict__ x3key, int* __restrict__ b2max) {
    __shared__ unsigned short As[16][904];  // 28.9 KB -> 5 blocks/CU
    const int tid = threadIdx.x;
    const int w = tid >> 6;   // wave 0..3
    const int l = tid & 63;
    const int m = l & 15, q = l >> 4;
    const int i = l & 31, hp = l >> 5;
    float wa0 = 0.f, wa1 = 0.f, wa2 = 0.f, ba0 = 0.f;
    if (l < 25) { wa0 = w2a[l]; wa1 = w2a[25 + l]; wa2 = w2a[50 + l]; ba0 = b2a[l]; }
    const float inv = 0.5f / __uint_as_float(maxabs[0]);
    const int ntiles = (C1n + 15) / 16;   // 938
    for (int tile = blockIdx.x; tile < ntiles; tile += gridDim.x) {
        const int base = tile * 16;
        // ---- phase 1: each wave gathers 4 dst rows; masked batch-4, linear loads ----
#pragma unroll
        for (int s4 = 0; s4 < 4; ++s4) {
            const int row = w * 4 + s4;
            const int d = base + row;
            if (d < C1n) {
                const unsigned e0 = rp2[d], e1 = rp2[d + 1];
                float acc[13];
#pragma unroll
                for (int r = 0; r < 13; ++r) acc[r] = 0.f;
                for (unsigned p = e0; p < e1; p += 4) {
                    float4 cv[4];
                    float xv[4];
#pragma unroll
                    for (int b = 0; b < 4; ++b) {
                        const unsigned pp = (p + b < e1) ? p + b : e1 - 1;
                        cv[b] = C2R[pp];                       // linear
                        float xl = XP2Rf[(size_t)pp * 32 + i]; // linear, independent
                        xv[b] = (p + b < e1) ? xl : 0.f;
                    }
#pragma unroll
                    for (int b = 0; b < 4; ++b) {
                        float a = ba0 + (cv[b].x * inv + 0.5f) * wa0 + (cv[b].y * inv + 0.5f) * wa1
                                      + (cv[b].z * inv + 0.5f) * wa2;
                        float hown = (l == 25) ? 1.f : fmaxf(a, 0.f);
#pragma unroll
                        for (int r = 0; r < 13; ++r)
                            acc[r] += __shfl(hown, 2 * r + hp, 64) * xv[b];
                    }
                }
                const float dinv = 1.f / fmaxf((float)(e1 - e0), 1.f);
#pragma unroll
                for (int r = 0; r < 13; ++r) As[row][r * 64 + l] = f2bf(acc[r] * dinv);
                As[row][832 + l] = f2bf((l < 32) ? xp[d * 32 + l] : (l == 32 ? 1.f : 0.f));
                if (l == 0) atomicMax(&b2max[cl2[d]], bpmax[d]);   // aux fused here
            } else {
#pragma unroll
                for (int r = 0; r < 13; ++r) As[row][r * 64 + l] = 0;
                As[row][832 + l] = 0;
            }
        }
        __syncthreads();
        // ---- phase 2: wave w MFMAs quadrant w (all 4 waves busy) ----
        {
            f32x4 a4 = {0.f, 0.f, 0.f, 0.f};
#pragma unroll 4
            for (int s = 0; s < 28; ++s) {
                short8 av = *reinterpret_cast<const short8*>(&As[m][s * 32 + q * 8]);
                short8 bv = *reinterpret_cast<const short8*>(&W2T[(w * 16 + m) * 896 + s * 32 + q * 8]);
                a4 = __builtin_amdgcn_mfma_f32_16x16x32_bf16(av, bv, a4, 0, 0, 0);
            }
#pragma unroll
            for (int r = 0; r < 4; ++r) {
                const int row = base + q * 4 + r;
                if (row < C1n) {
                    const int c2 = cl2[row];
                    float v = elu(a4[r]);
                    atomicMax(&x3key[c2 * 64 + w * 16 + m], fkey(v));
                }
            }
        }
        __syncthreads();
    }
}

// ---- two-stage batch reduction: LDS partials, then 1 global atomic/slot ----
__global__ __launch_bounds__(256) void gacc_kernel(
    const unsigned* __restrict__ x3key, const int* __restrict__ b2max,
    float* __restrict__ gsum, float* __restrict__ gcnt) {
    __shared__ float ls[Bb * 64];
    __shared__ float lc[Bb];
    const int t = threadIdx.x;
    for (int i = t; i < Bb * 64; i += 256) ls[i] = 0.f;
    if (t < Bb) lc[t] = 0.f;
    __syncthreads();
    const int o = t & 63;
    const int cs = t >> 6;
    for (int c = blockIdx.x * 4 + cs; c < C2n; c += gridDim.x * 4) {
        int b = b2max[c];
        unsigned k = x3key[c * 64 + o];
        float v = k ? funkey(k) : 0.f;
        atomicAdd(&ls[b * 64 + o], v);
        if (o == 0) atomicAdd(&lc[b], 1.f);
    }
    __syncthreads();
    for (int i = t; i < Bb * 64; i += 256) {
        float v = ls[i];
        if (v != 0.f) atomicAdd(&gsum[i], v);
    }
    if (t < Bb) {
        float v = lc[t];
        if (v != 0.f) atomicAdd(&gcnt[t], v);
    }
}

__global__ void head_kernel(const float* __restrict__ gsum, const float* __restrict__ gcnt,
                            const float* __restrict__ fc1w, const float* __restrict__ fc1b,
                            const float* __restrict__ fc2w, const float* __restrict__ fc2b,
                            float* __restrict__ out) {
    __shared__ float g[16 * 64];
    __shared__ float hb[16 * 128];
    __shared__ float lg[16 * 10];
    __shared__ float rowm[16];
    int t = threadIdx.x;
    for (int idx = t; idx < 16 * 64; idx += 256) {
        int b = idx >> 6;
        g[idx] = gsum[idx] / fmaxf(gcnt[b], 1.f);
    }
    __syncthreads();
    for (int idx = t; idx < 16 * 128; idx += 256) {
        int b = idx >> 7, j = idx & 127;
        float a = fc1b[j];
        for (int i = 0; i < 64; ++i) a += g[b * 64 + i] * fc1w[i * 128 + j];
        hb[idx] = elu(a);
    }
    __syncthreads();
    for (int idx = t; idx < 160; idx += 256) {
        int b = idx / 10, c = idx % 10;
        float a = fc2b[c];
        for (int i = 0; i < 128; ++i) a += hb[b * 128 + i] * fc2w[i * 10 + c];
        lg[idx] = a;
    }
    __syncthreads();
    if (t < 16) {
        float m = -1e30f;
        for (int c = 0; c < 10; ++c) m = fmaxf(m, lg[t * 10 + c]);
        float s = 0.f;
        for (int c = 0; c < 10; ++c) s += expf(lg[t * 10 + c] - m);
        rowm[t] = m + logf(s);
    }
    __syncthreads();
    for (int idx = t; idx < 160; idx += 256) out[idx] = lg[idx] - rowm[idx / 10];
}

extern "C" void kernel_launch(void* const* d_in, const int* in_sizes, int n_in,
                              void* d_out, int out_size, void* d_ws, size_t ws_size,
                              hipStream_t stream) {
    const float* x     = (const float*)d_in[0];
    const float* ea    = (const float*)d_in[1];
    const float* pos   = (const float*)d_in[2];
    const int*   ei    = (const int*)d_in[3];
    const int*   batch = (const int*)d_in[4];
    const int*   cl1   = (const int*)d_in[5];
    const int*   ei2   = (const int*)d_in[6];
    const int*   cl2   = (const int*)d_in[7];
    const float* w1a   = (const float*)d_in[8];
    const float* b1a   = (const float*)d_in[9];
    const float* w1b   = (const float*)d_in[10];
    const float* b1b   = (const float*)d_in[11];
    const float* root1 = (const float*)d_in[12];
    const float* bias1 = (const float*)d_in[13];
    const float* w2a   = (const float*)d_in[14];
    const float* b2a   = (const float*)d_in[15];
    const float* w2b   = (const float*)d_in[16];
    const float* b2b   = (const float*)d_in[17];
    const float* root2 = (const float*)d_in[18];
    const float* bias2 = (const float*)d_in[19];
    const float* fc1w  = (const float*)d_in[20];
    const float* fc1b  = (const float*)d_in[21];
    const float* fc2w  = (const float*)d_in[22];
    const float* fc2b  = (const float*)d_in[23];
    float* out = (float*)d_out;

    float* ws = (float*)d_ws;
    unsigned* xpkey  = (unsigned*)(ws + OFF_XPKEY);
    float*    possum = ws + OFF_POSSUM;
    float*    cntc1  = ws + OFF_CNTC1;
    int*      bpmax  = (int*)(ws + OFF_BPMAX);
    unsigned* x3key  = (unsigned*)(ws + OFF_X3KEY);
    int*      b2max  = (int*)(ws + OFF_B2MAX);
    float*    gsum   = ws + OFF_GSUM;
    float*    gcnt   = ws + OFF_GCNT;
    unsigned* maxabs = (unsigned*)(ws + OFF_MAXABS);
    unsigned* deg1   = (unsigned*)(ws + OFF_DEG1);
    unsigned* fill1  = (unsigned*)(ws + OFF_FILL1);
    unsigned* deg2   = (unsigned*)(ws + OFF_DEG2);
    unsigned* fill2  = (unsigned*)(ws + OFF_FILL2);
    unsigned* rp1    = (unsigned*)(ws + OFF_RP1);
    unsigned* rp2    = (unsigned*)(ws + OFF_RP2);
    float*    posp   = ws + OFF_POSP;
    float*    xp     = ws + OFF_XP;
    unsigned short* W1T = (unsigned short*)(ws + OFF_W1T);
    unsigned short* W2T = (unsigned short*)(ws + OFF_W2T);
    float4*   EA1R  = (float4*)(ws + OFF_EA1R);
    float4*   C2R   = (float4*)(ws + OFF_C2R);
    float*    X1R   = ws + OFF_X1R;
    float*    XP2R  = ws + OFF_XP2R;

    hipMemsetAsync(ws, 0, (size_t)ZERO_ELEMS * 4, stream);

    wt_kernel<<<252, 256, 0, stream>>>(w1b, b1b, root1, bias1, w2b, b2b, root2, bias2, W1T, W2T);
    hist_kernel<<<(Ee + E2n + 255) / 256, 256, 0, stream>>>(ei, ei2, deg1, deg2);
    scan_both<<<2, 1024, 0, stream>>>(deg1, rp1, deg2, rp2);
    scatter1<<<(Ee + 255) / 256, 256, 0, stream>>>(x, ea, ei, rp1, fill1, EA1R, (float4*)X1R);
    g1conv1<<<1875, 256, 0, stream>>>(EA1R, X1R, x, rp1, w1a, b1a, W1T, pos, batch, cl1,
                                      xpkey, possum, cntc1, bpmax);
    pool1_final<<<(C1n * 32 + 255) / 256, 256, 0, stream>>>(xpkey, possum, cntc1, xp, posp);
    scatter2<<<(E2n + 255) / 256, 256, 0, stream>>>(posp, xp, ei2, rp2, fill2, C2R,
                                                    (float4*)XP2R, maxabs);
    g2conv2<<<938, 256, 0, stream>>>(C2R, XP2R, xp, maxabs, rp2, w2a, b2a, W2T, cl2, bpmax,
                                     x3key, b2max);
    gacc_kernel<<<32, 256, 0, stream>>>(x3key, b2max, gsum, gcnt);
    head_kernel<<<1, 256, 0, stream>>>(gsum, gcnt, fc1w, fc1b, fc2w, fc2b, out);
}

// Round 10
// 306.276 us; speedup vs baseline: 1.2264x; 1.0927x over previous
//
#include <hip/hip_runtime.h>
#include <hip/hip_bf16.h>

#define Nn 30000
#define Ee 400000
#define C1n 15000
#define E2n 100000
#define C2n 7500
#define Bb 16

// ---- workspace layout (float/u32 element offsets) ----
// zeroed region:
#define OFF_XPKEY   0         // C1*32 u32
#define OFF_POSSUM  480000    // C1*3
#define OFF_CNTC1   525000    // C1
#define OFF_BPMAX   540000    // C1 i32
#define OFF_X3KEY   555000    // C2*64 u32
#define OFF_B2MAX   1035000   // C2 i32
#define OFF_GSUM    1042500   // B*64
#define OFF_GCNT    1043524   // B
#define OFF_MAXABS  1043540   // 1 u32 (pad to 1043544)
#define OFF_DEG1    1043544   // N u32
#define OFF_FILL1   1073544   // N u32
#define OFF_DEG2    1103544   // C1 u32
#define OFF_FILL2   1118544   // C1 u32
#define OFF_CNTA    1133544   // 2 u32 range-allocator counters
#define ZERO_ELEMS  1133546
// non-zeroed:
#define OFF_BASE1   1133552   // N u32 (slot-range base per dst, graph 1)
#define OFF_BASE2   1163552   // C1 u32 (graph 2)
#define OFF_POSP    1178552   // C1*3
#define OFF_XP      1223552   // C1*32
#define OFF_W1T     1703552   // 32*224 bf16 = 3584 floats (padded K: j=k*8+i)
#define OFF_W2T     1707136   // 64*896 bf16 = 28672 floats
#define OFF_EA1R    1735808   // E float4 (ea0,ea1,ea2,-), dst-sorted
#define OFF_C2R     3335808   // E2 float4 (cart0,1,2,-), dst-sorted
#define OFF_X1R     3735808   // E*8 floats: x[src][0..5],0,0 dst-sorted (linear in g1)
#define OFF_XP2R    6935808   // E2*32 floats: xp[src] dst-sorted (linear in g2)
// total 10135808 floats ~ 40.5 MB

typedef __attribute__((ext_vector_type(8))) short short8;
typedef __attribute__((ext_vector_type(4))) float f32x4;

__device__ __forceinline__ unsigned fkey(float f) {
    unsigned u = __float_as_uint(f);
    return (u >> 31) ? ~u : (u | 0x80000000u);
}
__device__ __forceinline__ float funkey(unsigned k) {
    unsigned u = (k >> 31) ? (k ^ 0x80000000u) : ~k;
    return __uint_as_float(u);
}
__device__ __forceinline__ float elu(float a) { return a > 0.f ? a : expm1f(a); }

__device__ __forceinline__ unsigned short f2bf(float f) {
    unsigned u = __float_as_uint(f);
    unsigned lsb = (u >> 16) & 1u;
    u += 0x7fffu + lsb;  // round to nearest even
    return (unsigned short)(u >> 16);
}

// ==== CSR build: histogram (both graphs in one launch) ====
__global__ void hist_kernel(const int* __restrict__ ei, const int* __restrict__ ei2,
                            unsigned* __restrict__ deg1, unsigned* __restrict__ deg2) {
    int t = blockIdx.x * 256 + threadIdx.x;
    if (t < Ee) {
        atomicAdd(&deg1[ei[Ee + t]], 1u);
    } else if (t < Ee + E2n) {
        int e = t - Ee;
        atomicAdd(&deg2[ei2[E2n + e]], 1u);
    }
}

// ==== range allocator: replaces the serial prefix scan. The pipeline only
//      needs DISJOINT contiguous ranges per dst, not monotonic ones: wave-level
//      shfl scan + ONE atomicAdd per wave on a global counter. ====
__global__ void assign_kernel(const unsigned* __restrict__ deg1, unsigned* __restrict__ base1,
                              const unsigned* __restrict__ deg2, unsigned* __restrict__ base2,
                              unsigned* __restrict__ cnta) {
    const int nb1 = (Nn + 255) / 256;
    const unsigned* deg; unsigned* base; unsigned* cnt; int n, idx;
    if ((int)blockIdx.x < nb1) {
        deg = deg1; base = base1; cnt = cnta;     n = Nn;
        idx = blockIdx.x * 256 + threadIdx.x;
    } else {
        deg = deg2; base = base2; cnt = cnta + 1; n = C1n;
        idx = (blockIdx.x - nb1) * 256 + threadIdx.x;
    }
    const int lane = threadIdx.x & 63;
    unsigned d = (idx < n) ? deg[idx] : 0u;
    unsigned v = d;
#pragma unroll
    for (int off = 1; off < 64; off <<= 1) {
        unsigned u = __shfl_up(v, off, 64);
        if (lane >= off) v += u;
    }
    unsigned wtot = __shfl(v, 63, 64);          // wave total
    unsigned wbase = 0;
    if (lane == 63) wbase = atomicAdd(cnt, wtot);
    wbase = __shfl(wbase, 63, 64);
    if (idx < n) base[idx] = wbase + v - d;     // exclusive within wave
}

// ==== scatter1: edge attrs AND pre-gathered x[src] into dst-sorted slots ====
__global__ void scatter1(const float* __restrict__ x, const float* __restrict__ ea,
                         const int* __restrict__ ei,
                         const unsigned* __restrict__ base1, unsigned* __restrict__ fill1,
                         float4* __restrict__ EA1R, float4* __restrict__ X1R) {
    int e = blockIdx.x * 256 + threadIdx.x;
    if (e >= Ee) return;
    int d = ei[Ee + e];
    unsigned p = base1[d] + atomicAdd(&fill1[d], 1u);
    int src = ei[e];
    EA1R[p] = make_float4(ea[e * 3], ea[e * 3 + 1], ea[e * 3 + 2], 0.f);
    const float* xs = x + (size_t)src * 6;
    X1R[p * 2]     = make_float4(xs[0], xs[1], xs[2], xs[3]);
    X1R[p * 2 + 1] = make_float4(xs[4], xs[5], 0.f, 0.f);   // zero pad i=6,7
}

// ==== precompute transposed bf16 weight panels (K-major per col) ====
__global__ void wt_kernel(const float* __restrict__ w1b, const float* __restrict__ b1b,
                          const float* __restrict__ root1, const float* __restrict__ bias1,
                          const float* __restrict__ w2b, const float* __restrict__ b2b,
                          const float* __restrict__ root2, const float* __restrict__ bias2,
                          unsigned short* __restrict__ W1T, unsigned short* __restrict__ W2T) {
    int t = blockIdx.x * 256 + threadIdx.x;
    if (t < 32 * 224) {
        int col = t / 224, p = t % 224;
        float v = 0.f;
        if (p < 208) {
            int k = p >> 3, i = p & 7;
            if (i < 6) v = (k < 25) ? w1b[k * 192 + i * 32 + col] : b1b[i * 32 + col];
        }
        else if (p < 214)  { v = root1[(p - 208) * 32 + col]; }
        else if (p == 214) { v = bias1[col]; }
        W1T[t] = f2bf(v);
    } else {
        int u = t - 32 * 224;
        if (u < 64 * 896) {
            int col = u / 896, p = u % 896;
            float v;
            if (p < 800)       { int k = p / 32, i = p % 32; v = w2b[k * 2048 + i * 64 + col]; }
            else if (p < 832)  { int i = p - 800; v = b2b[i * 64 + col]; }
            else if (p < 864)  { v = root2[(p - 832) * 64 + col]; }
            else if (p == 864) { v = bias2[col]; }
            else v = 0.f;
            W2T[u] = f2bf(v);
        }
    }
}

// ==== fused g1 + conv1 + pool1, padded-K layout; all phase-1 loads linear ====
__global__ __launch_bounds__(256, 8) void g1conv1(
    const float4* __restrict__ EA1R, const float* __restrict__ X1Rf,
    const float* __restrict__ x,
    const unsigned* __restrict__ base1, const unsigned* __restrict__ deg1,
    const float* __restrict__ w1a, const float* __restrict__ b1a,
    const unsigned short* __restrict__ W1T,
    const float* __restrict__ pos, const int* __restrict__ batch, const int* __restrict__ cl1,
    unsigned* __restrict__ xpkey, float* __restrict__ possum,
    float* __restrict__ cntc1, int* __restrict__ bpmax) {
    __shared__ unsigned short As[16][232];  // bf16; stride 464B -> 2-way banks on b128 reads
    const int tid = threadIdx.x;
    const int w = tid >> 6;   // wave 0..3
    const int l = tid & 63;
    const int m = l & 15, q = l >> 4;
    const int i8 = l & 7;          // lane's x column (pad rows make i8=6,7 read 0)
    const int kq = l >> 3;         // k offset within each r-block
    float wa0 = 0.f, wa1 = 0.f, wa2 = 0.f, ba0 = 0.f;
    if (l < 25) { wa0 = w1a[l]; wa1 = w1a[25 + l]; wa2 = w1a[50 + l]; ba0 = b1a[l]; }
    const int ntiles = Nn / 16;   // 1875
    for (int tile = blockIdx.x; tile < ntiles; tile += gridDim.x) {
        const int base = tile * 16;
        // ---- phase 1: each wave gathers 4 dst rows; masked batch-4, linear loads ----
#pragma unroll
        for (int s4 = 0; s4 < 4; ++s4) {
            const int row = w * 4 + s4;
            const int d = base + row;
            const unsigned e0 = base1[d], e1 = e0 + deg1[d];
            float acc0 = 0.f, acc1 = 0.f, acc2 = 0.f, acc3 = 0.f;
            for (unsigned p = e0; p < e1; p += 4) {
                float4 ev[4];
                float xm[4];
#pragma unroll
                for (int b = 0; b < 4; ++b) {
                    const unsigned pp = (p + b < e1) ? p + b : e1 - 1;
                    ev[b] = EA1R[pp];                    // linear
                    float xv = X1Rf[(size_t)pp * 8 + i8];  // linear, independent of ev
                    xm[b] = (p + b < e1) ? xv : 0.f;     // mask tail edges
                }
#pragma unroll
                for (int b = 0; b < 4; ++b) {
                    float a = ba0 + ev[b].x * wa0 + ev[b].y * wa1 + ev[b].z * wa2;
                    float hown = (l == 25) ? 1.f : fmaxf(a, 0.f);
                    acc0 += __shfl(hown, kq, 64) * xm[b];
                    acc1 += __shfl(hown, 8 + kq, 64) * xm[b];
                    acc2 += __shfl(hown, 16 + kq, 64) * xm[b];
                    acc3 += __shfl(hown, 24 + kq, 64) * xm[b];  // k=24,25 live in lanes l<16
                }
            }
            const float dinv = 1.f / fmaxf((float)(e1 - e0), 1.f);
            As[row][l] = f2bf(acc0 * dinv);          // j 0..63   (k 0..7)
            As[row][64 + l] = f2bf(acc1 * dinv);     // j 64..127 (k 8..15)
            As[row][128 + l] = f2bf(acc2 * dinv);    // j 128..191(k 16..23)
            if (l < 16) {
                As[row][192 + l] = f2bf(acc3 * dinv);  // j 192..207 (k 24..25)
                float tail;
                if (l < 6)       tail = x[d * 6 + l];   // root slot
                else if (l == 6) tail = 1.f;            // bias slot (j=214)
                else             tail = 0.f;
                As[row][208 + l] = f2bf(tail);
            }
        }
        __syncthreads();
        // ---- phase 2: waves 0,1 MFMA the two 16-col quadrants; wave 2 pool aux ----
        if (w < 2) {
            f32x4 acc = {0.f, 0.f, 0.f, 0.f};
#pragma unroll
            for (int s = 0; s < 7; ++s) {
                short8 av = *reinterpret_cast<const short8*>(&As[m][s * 32 + q * 8]);
                short8 bv = *reinterpret_cast<const short8*>(&W1T[(w * 16 + m) * 224 + s * 32 + q * 8]);
                acc = __builtin_amdgcn_mfma_f32_16x16x32_bf16(av, bv, acc, 0, 0, 0);
            }
#pragma unroll
            for (int r = 0; r < 4; ++r) {
                const int row = base + q * 4 + r;
                const int c = cl1[row];
                float v = elu(acc[r]);
                atomicMax(&xpkey[c * 32 + w * 16 + m], fkey(v));
            }
        } else if (w == 2) {
            if (l < 16) {
                const int row = base + l;
                const int c = cl1[row];
#pragma unroll
                for (int j = 0; j < 3; ++j) atomicAdd(&possum[c * 3 + j], pos[row * 3 + j]);
                atomicAdd(&cntc1[c], 1.f);
                atomicMax(&bpmax[c], batch[row]);
            }
        }
        __syncthreads();
    }
}

__global__ void pool1_final(const unsigned* __restrict__ xpkey, const float* __restrict__ possum,
                            const float* __restrict__ cntc1, float* __restrict__ xp,
                            float* __restrict__ posp) {
    int t = blockIdx.x * 256 + threadIdx.x;
    if (t >= C1n * 32) return;
    int c = t >> 5, o = t & 31;
    unsigned k = xpkey[t];
    xp[t] = k ? funkey(k) : 0.f;
    if (o < 3) posp[c * 3 + o] = possum[c * 3 + o] / fmaxf(cntc1[c], 1.f);
}

// ==== scatter2 (+fused cart + xp pre-gather): dst-sorted payloads ====
__global__ void scatter2(const float* __restrict__ posp, const float* __restrict__ xp,
                         const int* __restrict__ ei2,
                         const unsigned* __restrict__ base2, unsigned* __restrict__ fill2,
                         float4* __restrict__ C2R, float4* __restrict__ XP2R,
                         unsigned* __restrict__ maxabs) {
    int e = blockIdx.x * 256 + threadIdx.x;
    float mx = 0.f;
    if (e < E2n) {
        int s = ei2[e], d = ei2[E2n + e];
        float c0 = posp[s * 3]     - posp[d * 3];
        float c1 = posp[s * 3 + 1] - posp[d * 3 + 1];
        float c2 = posp[s * 3 + 2] - posp[d * 3 + 2];
        mx = fmaxf(fmaxf(fabsf(c0), fabsf(c1)), fabsf(c2));
        unsigned p = base2[d] + atomicAdd(&fill2[d], 1u);
        C2R[p] = make_float4(c0, c1, c2, 0.f);
        const float4* xs = reinterpret_cast<const float4*>(xp + (size_t)s * 32);
        float4* xd = XP2R + (size_t)p * 8;
#pragma unroll
        for (int j = 0; j < 8; ++j) xd[j] = xs[j];
    }
#pragma unroll
    for (int off = 32; off > 0; off >>= 1) mx = fmaxf(mx, __shfl_xor(mx, off));
    if ((threadIdx.x & 63) == 0) atomicMax(maxabs, __float_as_uint(mx));
}

// ==== fused g2 + conv2 + pool2: 256-thread blocks; linear phase-1 loads ====
__global__ __launch_bounds__(256, 5) void g2conv2(
    const float4* __restrict__ C2R, const float* __restrict__ XP2Rf,
    const float* __restrict__ xp,
    const unsigned* __restrict__ maxabs,
    const unsigned* __restrict__ base2, const unsigned* __restrict__ deg2,
    const float* __restrict__ w2a, const float* __restrict__ b2a,
    const unsigned short* __restrict__ W2T,
    const int* __restrict__ cl2, const int* __restrict__ bpmax,
    unsigned* __restrict__ x3key, int* __restrict__ b2max) {
    __shared__ unsigned short As[16][904];  // 28.9 KB -> 5 blocks/CU
    const int tid = threadIdx.x;
    const int w = tid >> 6;   // wave 0..3
    const int l = tid & 63;
    const int m = l & 15, q = l >> 4;
    const int i = l & 31, hp = l >> 5;
    float wa0 = 0.f, wa1 = 0.f, wa2 = 0.f, ba0 = 0.f;
    if (l < 25) { wa0 = w2a[l]; wa1 = w2a[25 + l]; wa2 = w2a[50 + l]; ba0 = b2a[l]; }
    const float inv = 0.5f / __uint_as_float(maxabs[0]);
    const int ntiles = (C1n + 15) / 16;   // 938
    for (int tile = blockIdx.x; tile < ntiles; tile += gridDim.x) {
        const int base = tile * 16;
        // ---- phase 1: each wave gathers 4 dst rows; masked batch-4, linear loads ----
#pragma unroll
        for (int s4 = 0; s4 < 4; ++s4) {
            const int row = w * 4 + s4;
            const int d = base + row;
            if (d < C1n) {
                const unsigned e0 = base2[d], e1 = e0 + deg2[d];
                float acc[13];
#pragma unroll
                for (int r = 0; r < 13; ++r) acc[r] = 0.f;
                for (unsigned p = e0; p < e1; p += 4) {
                    float4 cv[4];
                    float xv[4];
#pragma unroll
                    for (int b = 0; b < 4; ++b) {
                        const unsigned pp = (p + b < e1) ? p + b : e1 - 1;
                        cv[b] = C2R[pp];                       // linear
                        float xl = XP2Rf[(size_t)pp * 32 + i]; // linear, independent
                        xv[b] = (p + b < e1) ? xl : 0.f;
                    }
#pragma unroll
                    for (int b = 0; b < 4; ++b) {
                        float a = ba0 + (cv[b].x * inv + 0.5f) * wa0 + (cv[b].y * inv + 0.5f) * wa1
                                      + (cv[b].z * inv + 0.5f) * wa2;
                        float hown = (l == 25) ? 1.f : fmaxf(a, 0.f);
#pragma unroll
                        for (int r = 0; r < 13; ++r)
                            acc[r] += __shfl(hown, 2 * r + hp, 64) * xv[b];
                    }
                }
                const float dinv = 1.f / fmaxf((float)(e1 - e0), 1.f);
#pragma unroll
                for (int r = 0; r < 13; ++r) As[row][r * 64 + l] = f2bf(acc[r] * dinv);
                As[row][832 + l] = f2bf((l < 32) ? xp[d * 32 + l] : (l == 32 ? 1.f : 0.f));
                if (l == 0) atomicMax(&b2max[cl2[d]], bpmax[d]);   // aux fused here
            } else {
#pragma unroll
                for (int r = 0; r < 13; ++r) As[row][r * 64 + l] = 0;
                As[row][832 + l] = 0;
            }
        }
        __syncthreads();
        // ---- phase 2: wave w MFMAs quadrant w (all 4 waves busy) ----
        {
            f32x4 a4 = {0.f, 0.f, 0.f, 0.f};
#pragma unroll 4
            for (int s = 0; s < 28; ++s) {
                short8 av = *reinterpret_cast<const short8*>(&As[m][s * 32 + q * 8]);
                short8 bv = *reinterpret_cast<const short8*>(&W2T[(w * 16 + m) * 896 + s * 32 + q * 8]);
                a4 = __builtin_amdgcn_mfma_f32_16x16x32_bf16(av, bv, a4, 0, 0, 0);
            }
#pragma unroll
            for (int r = 0; r < 4; ++r) {
                const int row = base + q * 4 + r;
                if (row < C1n) {
                    const int c2 = cl2[row];
                    float v = elu(a4[r]);
                    atomicMax(&x3key[c2 * 64 + w * 16 + m], fkey(v));
                }
            }
        }
        __syncthreads();
    }
}

// ---- two-stage batch reduction: LDS partials, then 1 global atomic/slot ----
__global__ __launch_bounds__(256) void gacc_kernel(
    const unsigned* __restrict__ x3key, const int* __restrict__ b2max,
    float* __restrict__ gsum, float* __restrict__ gcnt) {
    __shared__ float ls[Bb * 64];
    __shared__ float lc[Bb];
    const int t = threadIdx.x;
    for (int i = t; i < Bb * 64; i += 256) ls[i] = 0.f;
    if (t < Bb) lc[t] = 0.f;
    __syncthreads();
    const int o = t & 63;
    const int cs = t >> 6;
    for (int c = blockIdx.x * 4 + cs; c < C2n; c += gridDim.x * 4) {
        int b = b2max[c];
        unsigned k = x3key[c * 64 + o];
        float v = k ? funkey(k) : 0.f;
        atomicAdd(&ls[b * 64 + o], v);
        if (o == 0) atomicAdd(&lc[b], 1.f);
    }
    __syncthreads();
    for (int i = t; i < Bb * 64; i += 256) {
        float v = ls[i];
        if (v != 0.f) atomicAdd(&gsum[i], v);
    }
    if (t < Bb) {
        float v = lc[t];
        if (v != 0.f) atomicAdd(&gcnt[t], v);
    }
}

__global__ void head_kernel(const float* __restrict__ gsum, const float* __restrict__ gcnt,
                            const float* __restrict__ fc1w, const float* __restrict__ fc1b,
                            const float* __restrict__ fc2w, const float* __restrict__ fc2b,
                            float* __restrict__ out) {
    __shared__ float g[16 * 64];
    __shared__ float hb[16 * 128];
    __shared__ float lg[16 * 10];
    __shared__ float rowm[16];
    int t = threadIdx.x;
    for (int idx = t; idx < 16 * 64; idx += 256) {
        int b = idx >> 6;
        g[idx] = gsum[idx] / fmaxf(gcnt[b], 1.f);
    }
    __syncthreads();
    for (int idx = t; idx < 16 * 128; idx += 256) {
        int b = idx >> 7, j = idx & 127;
        float a = fc1b[j];
        for (int i = 0; i < 64; ++i) a += g[b * 64 + i] * fc1w[i * 128 + j];
        hb[idx] = elu(a);
    }
    __syncthreads();
    for (int idx = t; idx < 160; idx += 256) {
        int b = idx / 10, c = idx % 10;
        float a = fc2b[c];
        for (int i = 0; i < 128; ++i) a += hb[b * 128 + i] * fc2w[i * 10 + c];
        lg[idx] = a;
    }
    __syncthreads();
    if (t < 16) {
        float m = -1e30f;
        for (int c = 0; c < 10; ++c) m = fmaxf(m, lg[t * 10 + c]);
        float s = 0.f;
        for (int c = 0; c < 10; ++c) s += expf(lg[t * 10 + c] - m);
        rowm[t] = m + logf(s);
    }
    __syncthreads();
    for (int idx = t; idx < 160; idx += 256) out[idx] = lg[idx] - rowm[idx / 10];
}

extern "C" void kernel_launch(void* const* d_in, const int* in_sizes, int n_in,
                              void* d_out, int out_size, void* d_ws, size_t ws_size,
                              hipStream_t stream) {
    const float* x     = (const float*)d_in[0];
    const float* ea    = (const float*)d_in[1];
    const float* pos   = (const float*)d_in[2];
    const int*   ei    = (const int*)d_in[3];
    const int*   batch = (const int*)d_in[4];
    const int*   cl1   = (const int*)d_in[5];
    const int*   ei2   = (const int*)d_in[6];
    const int*   cl2   = (const int*)d_in[7];
    const float* w1a   = (const float*)d_in[8];
    const float* b1a   = (const float*)d_in[9];
    const float* w1b   = (const float*)d_in[10];
    const float* b1b   = (const float*)d_in[11];
    const float* root1 = (const float*)d_in[12];
    const float* bias1 = (const float*)d_in[13];
    const float* w2a   = (const float*)d_in[14];
    const float* b2a   = (const float*)d_in[15];
    const float* w2b   = (const float*)d_in[16];
    const float* b2b   = (const float*)d_in[17];
    const float* root2 = (const float*)d_in[18];
    const float* bias2 = (const float*)d_in[19];
    const float* fc1w  = (const float*)d_in[20];
    const float* fc1b  = (const float*)d_in[21];
    const float* fc2w  = (const float*)d_in[22];
    const float* fc2b  = (const float*)d_in[23];
    float* out = (float*)d_out;

    float* ws = (float*)d_ws;
    unsigned* xpkey  = (unsigned*)(ws + OFF_XPKEY);
    float*    possum = ws + OFF_POSSUM;
    float*    cntc1  = ws + OFF_CNTC1;
    int*      bpmax  = (int*)(ws + OFF_BPMAX);
    unsigned* x3key  = (unsigned*)(ws + OFF_X3KEY);
    int*      b2max  = (int*)(ws + OFF_B2MAX);
    float*    gsum   = ws + OFF_GSUM;
    float*    gcnt   = ws + OFF_GCNT;
    unsigned* maxabs = (unsigned*)(ws + OFF_MAXABS);
    unsigned* deg1   = (unsigned*)(ws + OFF_DEG1);
    unsigned* fill1  = (unsigned*)(ws + OFF_FILL1);
    unsigned* deg2   = (unsigned*)(ws + OFF_DEG2);
    unsigned* fill2  = (unsigned*)(ws + OFF_FILL2);
    unsigned* cnta   = (unsigned*)(ws + OFF_CNTA);
    unsigned* base1  = (unsigned*)(ws + OFF_BASE1);
    unsigned* base2  = (unsigned*)(ws + OFF_BASE2);
    float*    posp   = ws + OFF_POSP;
    float*    xp     = ws + OFF_XP;
    unsigned short* W1T = (unsigned short*)(ws + OFF_W1T);
    unsigned short* W2T = (unsigned short*)(ws + OFF_W2T);
    float4*   EA1R  = (float4*)(ws + OFF_EA1R);
    float4*   C2R   = (float4*)(ws + OFF_C2R);
    float*    X1R   = ws + OFF_X1R;
    float*    XP2R  = ws + OFF_XP2R;

    hipMemsetAsync(ws, 0, (size_t)ZERO_ELEMS * 4, stream);

    wt_kernel<<<252, 256, 0, stream>>>(w1b, b1b, root1, bias1, w2b, b2b, root2, bias2, W1T, W2T);
    hist_kernel<<<(Ee + E2n + 255) / 256, 256, 0, stream>>>(ei, ei2, deg1, deg2);
    assign_kernel<<<(Nn + 255) / 256 + (C1n + 255) / 256, 256, 0, stream>>>(
        deg1, base1, deg2, base2, cnta);
    scatter1<<<(Ee + 255) / 256, 256, 0, stream>>>(x, ea, ei, base1, fill1, EA1R, (float4*)X1R);
    g1conv1<<<1875, 256, 0, stream>>>(EA1R, X1R, x, base1, deg1, w1a, b1a, W1T, pos, batch, cl1,
                                      xpkey, possum, cntc1, bpmax);
    pool1_final<<<(C1n * 32 + 255) / 256, 256, 0, stream>>>(xpkey, possum, cntc1, xp, posp);
    scatter2<<<(E2n + 255) / 256, 256, 0, stream>>>(posp, xp, ei2, base2, fill2, C2R,
                                                    (float4*)XP2R, maxabs);
    g2conv2<<<938, 256, 0, stream>>>(C2R, XP2R, xp, maxabs, base2, deg2, w2a, b2a, W2T,
                                     cl2, bpmax, x3key, b2max);
    gacc_kernel<<<32, 256, 0, stream>>>(x3key, b2max, gsum, gcnt);
    head_kernel<<<1, 256, 0, stream>>>(gsum, gcnt, fc1w, fc1b, fc2w, fc2b, out);
}